// Round 1
// baseline (290.377 us; speedup 1.0000x reference)
//
#include <hip/hip_runtime.h>
#include <stdint.h>

typedef _Float16 f16;
typedef __attribute__((ext_vector_type(4))) _Float16 f16x4;
typedef __attribute__((ext_vector_type(8))) _Float16 f16x8;
typedef __attribute__((ext_vector_type(4))) float f32x4;

#define NEG_FILL (-65504.0f)

// B=4, T=2048, D=512, H=8, dh=64; M = B*T = 8192 rows for all GEMMs.
#define TT 2048
#define DD 512
#define HH 8

__device__ __forceinline__ void gload_lds16(const void* gsrc, void* ldst) {
  __builtin_amdgcn_global_load_lds(
      (const __attribute__((address_space(1))) void*)gsrc,
      (__attribute__((address_space(3))) void*)ldst, 16, 0, 0);
}

// ---------------- fp32 -> fp16 convert (4 elems/thread) ----------------
__global__ __launch_bounds__(256) void cvt_f32_f16(const float* __restrict__ in,
                                                   f16* __restrict__ out, int n4) {
  int i = blockIdx.x * 256 + threadIdx.x;
  if (i < n4) {
    float4 v = ((const float4*)in)[i];
    f16x4 o;
    o.x = (_Float16)v.x; o.y = (_Float16)v.y;
    o.z = (_Float16)v.z; o.w = (_Float16)v.w;
    ((f16x4*)out)[i] = o;
  }
}

// ---------------- generic M=8192,N=512,K=512 GEMM:  C = A @ W^T + bias ----
// A: f16 [M][K] row-major.  W: f16 [N][K] row-major (torch Linear weight).
// MODE 0: out f16 at [b][h][t][c] (B,H,T,dh), value*(scale)   (qh / kh)
// MODE 1: out f16 at [b][h][c][t] (B,H,dh,T)                  (vhT)
// MODE 2: out f32 at [m][n]       (B,T,D)                     (final)
template <int MODE>
__global__ __launch_bounds__(256) void gemm_f16(const f16* __restrict__ A,
                                                const f16* __restrict__ W,
                                                const float* __restrict__ bias,
                                                void* __restrict__ out,
                                                float scale) {
  __shared__ __align__(16) f16 Alds[128 * 64];
  __shared__ __align__(16) f16 Blds[128 * 64];

  const int K = 512;
  const int nt = blockIdx.x & 3;    // N / 128 = 4
  const int mt = blockIdx.x >> 2;   // M / 128 = 64
  const int tid = threadIdx.x;
  const int w = tid >> 6, lane = tid & 63;
  const int l15 = lane & 15, lg = lane >> 4;
  const int wm = w >> 1, wn = w & 1;

  const f32x4 vzero = {0.f, 0.f, 0.f, 0.f};
  f32x4 acc[4][4];
#pragma unroll
  for (int mi = 0; mi < 4; ++mi)
#pragma unroll
    for (int nj = 0; nj < 4; ++nj) acc[mi][nj] = vzero;

  for (int kt = 0; kt < 8; ++kt) {  // K / 64
    // ---- stage A and W tiles (128 x 64 f16 each) via global_load_lds ----
    // linear LDS dest; source pre-swizzled so that swizzled reads are
    // conflict-light:  LDS granule (row, j) holds global chunk (row, j^(row&7))
#pragma unroll
    for (int i = 0; i < 4; ++i) {
      int g = (i * 4 + w) * 64 + lane;   // granule 0..1023
      int row = g >> 3, jj = g & 7;
      int kb = kt * 128 + (((jj ^ (row & 7)) << 4));  // byte offset in row
      gload_lds16((const char*)A + (size_t)(mt * 128 + row) * (K * 2) + kb,
                  (char*)Alds + (i * 4 + w) * 1024);
      gload_lds16((const char*)W + (size_t)(nt * 128 + row) * (K * 2) + kb,
                  (char*)Blds + (i * 4 + w) * 1024);
    }
    __syncthreads();

#pragma unroll
    for (int h2 = 0; h2 < 2; ++h2) {
      f16x8 af[4], bf[4];
#pragma unroll
      for (int mi = 0; mi < 4; ++mi) {
        int row = wm * 64 + mi * 16 + l15;
        int bo = (h2 * 64 + (lg << 4)) ^ ((row & 7) << 4);
        af[mi] = *(const f16x8*)((const char*)Alds + row * 128 + bo);
      }
#pragma unroll
      for (int nj = 0; nj < 4; ++nj) {
        int row = wn * 64 + nj * 16 + l15;
        int bo = (h2 * 64 + (lg << 4)) ^ ((row & 7) << 4);
        bf[nj] = *(const f16x8*)((const char*)Blds + row * 128 + bo);
      }
#pragma unroll
      for (int mi = 0; mi < 4; ++mi)
#pragma unroll
        for (int nj = 0; nj < 4; ++nj)
          acc[mi][nj] = __builtin_amdgcn_mfma_f32_16x16x32_f16(
              af[mi], bf[nj], acc[mi][nj], 0, 0, 0);
    }
    __syncthreads();
  }

  // ---- epilogue; D layout: col = lane&15, row = (lane>>4)*4 + r ----
  const int base_m = mt * 128 + wm * 64;
  const int base_n = nt * 128 + wn * 64;
#pragma unroll
  for (int mi = 0; mi < 4; ++mi) {
#pragma unroll
    for (int nj = 0; nj < 4; ++nj) {
      int n = base_n + nj * 16 + l15;
      float bv = bias[n];
#pragma unroll
      for (int r = 0; r < 4; ++r) {
        int m = base_m + mi * 16 + (lg << 2) + r;
        float val = acc[mi][nj][r] + bv;
        if (MODE == 0) {
          int b = m >> 11, t = m & (TT - 1), h = n >> 6, c = n & 63;
          ((f16*)out)[(((size_t)(b * HH + h) * TT + t) << 6) + c] =
              (f16)(val * scale);
        } else if (MODE == 1) {
          int b = m >> 11, t = m & (TT - 1), h = n >> 6, c = n & 63;
          ((f16*)out)[(((size_t)(b * HH + h) * 64 + c) << 11) + t] = (f16)val;
        } else {
          ((float*)out)[(size_t)m * DD + n] = val;
        }
      }
    }
  }
}

// ---------------- flash attention ----------------
// qh, kh: f16 (B,H,T,64)   (qh pre-scaled by 512^-0.5)
// vhT:    f16 (B,H,64,T)
// att out: f16 (B,T,512)   row-major, ready to be GEMM A operand
__global__ __launch_bounds__(256) void attn_k(const f16* __restrict__ qh,
                                              const f16* __restrict__ kh,
                                              const f16* __restrict__ vhT,
                                              const int* __restrict__ mask,
                                              f16* __restrict__ att) {
  __shared__ __align__(16) f16 Klds[64 * 64];
  __shared__ __align__(16) f16 Vlds[64 * 64];
  __shared__ __align__(16) f16 Plds[4][16 * 72];  // +8 pad per row: 2-way only

  const int bh = blockIdx.x >> 5;  // 0..31
  const int qt = blockIdx.x & 31;  // q tile of 64 rows
  const int b = bh >> 3, h = bh & 7;
  const f16* Q = qh + (size_t)bh * TT * 64;
  const f16* Kp = kh + (size_t)bh * TT * 64;
  const f16* Vp = vhT + (size_t)bh * 64 * TT;
  const int* mp = mask + b * TT;

  const int tid = threadIdx.x;
  const int w = tid >> 6, lane = tid & 63;
  const int l15 = lane & 15, lg = lane >> 4;

  // Q fragments in registers (A-operand; row = lane&15, k-slot contiguous)
  const int qrowA = qt * 64 + w * 16 + l15;
  f16x8 qf[2];
  qf[0] = *(const f16x8*)(Q + (size_t)qrowA * 64 + lg * 8);
  qf[1] = *(const f16x8*)(Q + (size_t)qrowA * 64 + 32 + lg * 8);

  const f32x4 vzero = {0.f, 0.f, 0.f, 0.f};
  float m_r[4], l_r[4];
  f32x4 o[4];
#pragma unroll
  for (int r = 0; r < 4; ++r) { m_r[r] = -INFINITY; l_r[r] = 0.f; }
#pragma unroll
  for (int cf = 0; cf < 4; ++cf) o[cf] = vzero;

  for (int kt = 0; kt < 32; ++kt) {  // T / 64 k-tiles
    // ---- stage K tile (64x64, row=k, col=c) and V^T tile (64x64, row=c,col=t)
#pragma unroll
    for (int i = 0; i < 2; ++i) {
      int g = (i * 4 + w) * 64 + lane;  // granule 0..511
      int row = g >> 3, jj = g & 7;
      int cb = ((jj ^ (row & 7)) << 3);  // f16 index of 16B chunk in row
      gload_lds16(Kp + (size_t)(kt * 64 + row) * 64 + cb,
                  (char*)Klds + (i * 4 + w) * 1024);
      gload_lds16(Vp + (size_t)row * TT + kt * 64 + cb,
                  (char*)Vlds + (i * 4 + w) * 1024);
    }
    __syncthreads();

    // ---- S = Q K^T  (16 q-rows x 64 k-cols per wave) ----
    f32x4 s[4];
#pragma unroll
    for (int f = 0; f < 4; ++f) s[f] = vzero;
#pragma unroll
    for (int h2 = 0; h2 < 2; ++h2) {
#pragma unroll
      for (int f = 0; f < 4; ++f) {
        int krow = f * 16 + l15;
        int bo = (h2 * 64 + (lg << 4)) ^ ((krow & 7) << 4);
        f16x8 kf = *(const f16x8*)((const char*)Klds + krow * 128 + bo);
        s[f] = __builtin_amdgcn_mfma_f32_16x16x32_f16(qf[h2], kf, s[f], 0, 0, 0);
      }
    }

    // ---- mask + online softmax ----
    float sv[4][4], pv[4][4];
#pragma unroll
    for (int f = 0; f < 4; ++f) {
      int col = kt * 64 + f * 16 + l15;
      bool keep = (mp[col] != 0);
#pragma unroll
      for (int r = 0; r < 4; ++r) sv[f][r] = keep ? s[f][r] : NEG_FILL;
    }
#pragma unroll
    for (int r = 0; r < 4; ++r) {
      float mx = fmaxf(fmaxf(sv[0][r], sv[1][r]), fmaxf(sv[2][r], sv[3][r]));
      mx = fmaxf(mx, __shfl_xor(mx, 1));
      mx = fmaxf(mx, __shfl_xor(mx, 2));
      mx = fmaxf(mx, __shfl_xor(mx, 4));
      mx = fmaxf(mx, __shfl_xor(mx, 8));
      float mnew = fmaxf(m_r[r], mx);
      float corr = __expf(m_r[r] - mnew);
      float rs = 0.f;
#pragma unroll
      for (int f = 0; f < 4; ++f) {
        float p = __expf(sv[f][r] - mnew);
        pv[f][r] = p;
        rs += p;
      }
      rs += __shfl_xor(rs, 1);
      rs += __shfl_xor(rs, 2);
      rs += __shfl_xor(rs, 4);
      rs += __shfl_xor(rs, 8);
      m_r[r] = mnew;
      l_r[r] = l_r[r] * corr + rs;
#pragma unroll
      for (int cf = 0; cf < 4; ++cf) o[cf][r] *= corr;
    }

    // ---- P -> LDS (per-wave buffer), then O += P @ V ----
#pragma unroll
    for (int f = 0; f < 4; ++f)
#pragma unroll
      for (int r = 0; r < 4; ++r)
        Plds[w][(lg * 4 + r) * 72 + f * 16 + l15] = (f16)pv[f][r];

#pragma unroll
    for (int h2 = 0; h2 < 2; ++h2) {
      f16x8 pa = *(const f16x8*)(&Plds[w][l15 * 72 + h2 * 32 + lg * 8]);
#pragma unroll
      for (int cf = 0; cf < 4; ++cf) {
        int vrow = cf * 16 + l15;
        int bo = (h2 * 64 + (lg << 4)) ^ ((vrow & 7) << 4);
        f16x8 vf = *(const f16x8*)((const char*)Vlds + vrow * 128 + bo);
        o[cf] = __builtin_amdgcn_mfma_f32_16x16x32_f16(pa, vf, o[cf], 0, 0, 0);
      }
    }
    __syncthreads();
  }

  // ---- epilogue: divide by l, write att (B,T,512) ----
#pragma unroll
  for (int cf = 0; cf < 4; ++cf) {
#pragma unroll
    for (int r = 0; r < 4; ++r) {
      int qrow = qt * 64 + w * 16 + lg * 4 + r;
      float val = o[cf][r] / l_r[r];
      att[((size_t)(b * TT + qrow) << 9) + h * 64 + cf * 16 + l15] = (f16)val;
    }
  }
}

// ---------------- host launch ----------------
extern "C" void kernel_launch(void* const* d_in, const int* in_sizes, int n_in,
                              void* d_out, int out_size, void* d_ws, size_t ws_size,
                              hipStream_t stream) {
  (void)in_sizes; (void)n_in; (void)out_size; (void)ws_size;
  const float* q = (const float*)d_in[0];
  const float* k = (const float*)d_in[1];
  const float* v = (const float*)d_in[2];
  const int* mask = (const int*)d_in[3];
  const float* Wq = (const float*)d_in[4];
  const float* bq = (const float*)d_in[5];
  const float* Wk = (const float*)d_in[6];
  const float* bk = (const float*)d_in[7];
  const float* Wv = (const float*)d_in[8];
  const float* bv = (const float*)d_in[9];
  const float* Wo = (const float*)d_in[10];
  const float* bo = (const float*)d_in[11];

  char* ws = (char*)d_ws;
  const size_t SZ = (size_t)8192 * 512 * 2;  // 8 MiB per (B,T,D) f16 tensor
  f16* q16 = (f16*)(ws + 0 * SZ);
  f16* k16 = (f16*)(ws + 1 * SZ);
  f16* v16 = (f16*)(ws + 2 * SZ);
  f16* qhp = (f16*)(ws + 3 * SZ);
  f16* khp = (f16*)(ws + 4 * SZ);
  f16* vhT = (f16*)(ws + 5 * SZ);
  f16* w16 = (f16*)(ws + 6 * SZ);  // 4 x 512x512 f16
  f16* wq16 = w16;
  f16* wk16 = w16 + 262144;
  f16* wv16 = w16 + 2 * 262144;
  f16* wo16 = w16 + 3 * 262144;
  f16* att = (f16*)(ws + 0 * SZ);  // alias q16 (dead after qh GEMM)

  // converts
  cvt_f32_f16<<<4096, 256, 0, stream>>>(q, q16, 1048576);
  cvt_f32_f16<<<4096, 256, 0, stream>>>(k, k16, 1048576);
  cvt_f32_f16<<<4096, 256, 0, stream>>>(v, v16, 1048576);
  cvt_f32_f16<<<256, 256, 0, stream>>>(Wq, wq16, 65536);
  cvt_f32_f16<<<256, 256, 0, stream>>>(Wk, wk16, 65536);
  cvt_f32_f16<<<256, 256, 0, stream>>>(Wv, wv16, 65536);
  cvt_f32_f16<<<256, 256, 0, stream>>>(Wo, wo16, 65536);

  const float scale = 0.044194173824159216f;  // 512^-0.5 (dim_a = D, not dh!)
  gemm_f16<0><<<256, 256, 0, stream>>>(q16, wq16, bq, qhp, scale);
  gemm_f16<0><<<256, 256, 0, stream>>>(k16, wk16, bk, khp, 1.0f);
  gemm_f16<1><<<256, 256, 0, stream>>>(v16, wv16, bv, vhT, 1.0f);

  attn_k<<<1024, 256, 0, stream>>>(qhp, khp, vhT, mask, att);

  gemm_f16<2><<<256, 256, 0, stream>>>(att, wo16, bo, d_out, 1.0f);
}

// Round 3
// 237.602 us; speedup vs baseline: 1.2221x; 1.2221x over previous
//
#include <hip/hip_runtime.h>
#include <stdint.h>

typedef _Float16 f16;
typedef __attribute__((ext_vector_type(4))) _Float16 f16x4;
typedef __attribute__((ext_vector_type(8))) _Float16 f16x8;
typedef __attribute__((ext_vector_type(4))) float f32x4;
typedef __attribute__((ext_vector_type(16))) float f32x16;
typedef __attribute__((ext_vector_type(4))) int int4v;

#define TT 2048
#define HH 8

static __device__ __forceinline__ void gload_lds16(const void* g, void* l) {
  __builtin_amdgcn_global_load_lds((const __attribute__((address_space(1))) void*)g,
                                   (__attribute__((address_space(3))) void*)l, 16, 0, 0);
}

static __device__ __forceinline__ int pkf16(float a, float b) {
  auto h = __builtin_amdgcn_cvt_pkrtz(a, b);  // __fp16 ext_vector(2)
  return __builtin_bit_cast(int, h);
}

static __device__ __forceinline__ void plswap(int& a, int& b) {
  asm("v_permlane32_swap_b32 %0, %1" : "+v"(a), "+v"(b));
}

// Build PV A-fragment (rows=q=lane&31, k-slots=(lane>>5)*8+j) from swapped-QK
// D regs p0..p7 (k = (r&3)+8*(r>>2)+4*hi within a 16-k block).
static __device__ __forceinline__ f16x8 mkpa(float p0, float p1, float p2, float p3,
                                             float p4, float p5, float p6, float p7) {
  int a0 = pkf16(p0, p1), a1 = pkf16(p2, p3);
  int b0 = pkf16(p4, p5), b1 = pkf16(p6, p7);
  plswap(a0, b0);
  plswap(a1, b1);
  int4v w = {a0, a1, b0, b1};
  return __builtin_bit_cast(f16x8, w);
}

// ---------------- converts ----------------
__global__ __launch_bounds__(256) void cvt3(const float* __restrict__ a,
                                            const float* __restrict__ b,
                                            const float* __restrict__ c,
                                            f16* __restrict__ dst) {
  int g = blockIdx.x * 256 + threadIdx.x;  // 3 * 1048576 float4
  int sel = g >> 20, off = g & 1048575;
  const float* s = sel == 0 ? a : sel == 1 ? b : c;
  float4 v = ((const float4*)s)[off];
  f16x4 o = {(_Float16)v.x, (_Float16)v.y, (_Float16)v.z, (_Float16)v.w};
  ((f16x4*)dst)[g] = o;
}

__global__ __launch_bounds__(256) void cvt4(const float* __restrict__ a,
                                            const float* __restrict__ b,
                                            const float* __restrict__ c,
                                            const float* __restrict__ d,
                                            f16* __restrict__ dst) {
  int g = blockIdx.x * 256 + threadIdx.x;  // 4 * 65536 float4
  int sel = g >> 16, off = g & 65535;
  const float* s = sel == 0 ? a : sel == 1 ? b : (sel == 2 ? c : d);
  float4 v = ((const float4*)s)[off];
  f16x4 o = {(_Float16)v.x, (_Float16)v.y, (_Float16)v.z, (_Float16)v.w};
  ((f16x4*)dst)[g] = o;
}

// ---------------- masked-key count per batch ----------------
__global__ __launch_bounds__(256) void cntk(const int* __restrict__ mask,
                                            float* __restrict__ cnt) {
  __shared__ int red[256];
  int b = blockIdx.x, t = threadIdx.x;
  int s = 0;
#pragma unroll
  for (int i = 0; i < 8; ++i) s += (mask[b * 2048 + t * 8 + i] == 0) ? 1 : 0;
  red[t] = s;
  __syncthreads();
  for (int off = 128; off > 0; off >>= 1) {
    if (t < off) red[t] += red[t + off];
    __syncthreads();
  }
  if (t == 0) cnt[b] = (float)red[0];
}

// ---------------- merged q/k/v projection GEMM ----------------
// grid 768: prob = bid>>8 (0=q,1=k,2=v); 128x128 tile, K=512, BK=64.
// prob0: qh  (B,H,T,64) scaled by 512^-0.5 * log2(e)
// prob1: kh  (B,H,T,64) zeroed on masked t
// prob2: vhT (B,H,64,T) zeroed on masked t
__global__ __launch_bounds__(256) void gemm_qkv(
    const f16* __restrict__ q16, const f16* __restrict__ k16,
    const f16* __restrict__ v16, const f16* __restrict__ wq,
    const f16* __restrict__ wk, const f16* __restrict__ wv,
    const float* __restrict__ bq, const float* __restrict__ bk,
    const float* __restrict__ bv, const int* __restrict__ mask,
    f16* __restrict__ qhp, f16* __restrict__ khp, f16* __restrict__ vhT,
    float scale) {
  __shared__ __align__(16) f16 Alds[128 * 64];
  __shared__ __align__(16) f16 Blds[128 * 64];

  const int prob = blockIdx.x >> 8;
  const int sub = blockIdx.x & 255;
  const int nt = sub & 3, mt = sub >> 2;
  const f16* A = prob == 0 ? q16 : (prob == 1 ? k16 : v16);
  const f16* W = prob == 0 ? wq : (prob == 1 ? wk : wv);
  const float* bias = prob == 0 ? bq : (prob == 1 ? bk : bv);

  const int tid = threadIdx.x;
  const int w = tid >> 6, lane = tid & 63;
  const int l15 = lane & 15, lg = lane >> 4;
  const int wm = w >> 1, wn = w & 1;

  f32x4 acc[4][4];
#pragma unroll
  for (int mi = 0; mi < 4; ++mi)
#pragma unroll
    for (int nj = 0; nj < 4; ++nj) acc[mi][nj] = {};

  for (int kt = 0; kt < 8; ++kt) {
#pragma unroll
    for (int i = 0; i < 4; ++i) {
      int g = (i * 4 + w) * 64 + lane;
      int row = g >> 3, jj = g & 7;
      int kb = kt * 128 + ((jj ^ (row & 7)) << 4);
      gload_lds16((const char*)A + (size_t)(mt * 128 + row) * 1024 + kb,
                  (char*)Alds + g * 16);
      gload_lds16((const char*)W + (size_t)(nt * 128 + row) * 1024 + kb,
                  (char*)Blds + g * 16);
    }
    __syncthreads();

#pragma unroll
    for (int h2 = 0; h2 < 2; ++h2) {
      f16x8 af[4], bf[4];
#pragma unroll
      for (int mi = 0; mi < 4; ++mi) {
        int row = wm * 64 + mi * 16 + l15;
        int bo = (h2 * 64 + (lg << 4)) ^ ((row & 7) << 4);
        af[mi] = *(const f16x8*)((const char*)Alds + row * 128 + bo);
      }
#pragma unroll
      for (int nj = 0; nj < 4; ++nj) {
        int row = wn * 64 + nj * 16 + l15;
        int bo = (h2 * 64 + (lg << 4)) ^ ((row & 7) << 4);
        bf[nj] = *(const f16x8*)((const char*)Blds + row * 128 + bo);
      }
#pragma unroll
      for (int mi = 0; mi < 4; ++mi)
#pragma unroll
        for (int nj = 0; nj < 4; ++nj)
          acc[mi][nj] = __builtin_amdgcn_mfma_f32_16x16x32_f16(
              af[mi], bf[nj], acc[mi][nj], 0, 0, 0);
    }
    __syncthreads();
  }

  const int base_m = mt * 128 + wm * 64;
  const int base_n = nt * 128 + wn * 64;
  float bb[4];
#pragma unroll
  for (int nj = 0; nj < 4; ++nj) bb[nj] = bias[base_n + nj * 16 + l15];

#pragma unroll
  for (int mi = 0; mi < 4; ++mi) {
#pragma unroll
    for (int r = 0; r < 4; ++r) {
      int m = base_m + mi * 16 + (lg << 2) + r;
      int b = m >> 11, t = m & (TT - 1);
      float sc = (prob == 0) ? scale : (mask[(b << 11) + t] ? 1.f : 0.f);
#pragma unroll
      for (int nj = 0; nj < 4; ++nj) {
        int n = base_n + nj * 16 + l15;
        int h = n >> 6, c = n & 63;
        float val = (acc[mi][nj][r] + bb[nj]) * sc;
        if (prob == 2)
          vhT[(((size_t)(b * HH + h) * 64 + c) << 11) + t] = (f16)val;
        else if (prob == 1)
          khp[(((size_t)(b * HH + h) * TT + t) << 6) + c] = (f16)val;
        else
          qhp[(((size_t)(b * HH + h) * TT + t) << 6) + c] = (f16)val;
      }
    }
  }
}

// ---------------- flash attention, 32x32 MFMA, swapped QK^T ----------------
// qh (B,H,T,64) prescaled by 512^-0.5*log2e; kh masked-row-zeroed;
// vhT (B,H,64,T) masked-col-zeroed; cnt[b] = # masked keys.
// 2 waves/block, 64 q-rows/block, 64-k tiles, double-buffered staging.
__global__ __launch_bounds__(128) void attn_k(
    const f16* __restrict__ qh, const f16* __restrict__ kh,
    const f16* __restrict__ vhT, const float* __restrict__ cnt,
    f16* __restrict__ att) {
  __shared__ __align__(16) f16 Klds[2][64 * 64];
  __shared__ __align__(16) f16 Vlds[2][64 * 64];
  __shared__ float Llds[2][32];

  const int bh = blockIdx.x >> 5;
  const int qt = blockIdx.x & 31;
  const int b = bh >> 3, h = bh & 7;
  const char* Kp = (const char*)(kh + (size_t)bh * (TT * 64));
  const char* Vp = (const char*)(vhT + (size_t)bh * (64 * TT));
  const f16* Q = qh + (size_t)bh * (TT * 64);

  const int tid = threadIdx.x;
  const int w = tid >> 6, lane = tid & 63;
  const int l31 = lane & 31, hi = lane >> 5;

  // Q fragments (B operand: col=l31=q, k-slots hi*8+j)
  const int qrow = qt * 64 + w * 32 + l31;
  f16x8 qf[4];
#pragma unroll
  for (int c = 0; c < 4; ++c)
    qf[c] = *(const f16x8*)(Q + (size_t)qrow * 64 + c * 16 + hi * 8);

  f32x16 o0 = {}, o1 = {};
  float lsum = 0.f;

  // prologue: stage tile 0 into buf 0
#pragma unroll
  for (int i = 0; i < 4; ++i) {
    int g = (i * 2 + w) * 64 + lane;
    int row = g >> 3, jj = g & 7;
    int sw = (jj ^ (row & 7)) << 4;
    gload_lds16(Kp + (size_t)row * 128 + sw, (char*)&Klds[0][0] + g * 16);
    gload_lds16(Vp + (size_t)row * 4096 + sw, (char*)&Vlds[0][0] + g * 16);
  }
  __syncthreads();

  for (int kt = 0; kt < 32; ++kt) {
    const int cur = kt & 1;
    if (kt < 31) {  // stage next tile into the other buffer
      const int nt_ = kt + 1;
#pragma unroll
      for (int i = 0; i < 4; ++i) {
        int g = (i * 2 + w) * 64 + lane;
        int row = g >> 3, jj = g & 7;
        int sw = (jj ^ (row & 7)) << 4;
        gload_lds16(Kp + (size_t)(nt_ * 64 + row) * 128 + sw,
                    (char*)&Klds[cur ^ 1][0] + g * 16);
        gload_lds16(Vp + (size_t)row * 4096 + nt_ * 128 + sw,
                    (char*)&Vlds[cur ^ 1][0] + g * 16);
      }
    }
    const char* Kl = (const char*)&Klds[cur][0];
    const char* Vl = (const char*)&Vlds[cur][0];

    // S^T = K @ Q^T : A=K (rows=k), B=Q (cols=q)
    f32x16 s0 = {}, s1 = {};
#pragma unroll
    for (int c = 0; c < 4; ++c) {
      int gk = ((c * 2 + hi) ^ (l31 & 7)) << 4;
      f16x8 kf0 = *(const f16x8*)(Kl + l31 * 128 + gk);
      f16x8 kf1 = *(const f16x8*)(Kl + (32 + l31) * 128 + gk);
      s0 = __builtin_amdgcn_mfma_f32_32x32x16_f16(kf0, qf[c], s0, 0, 0, 0);
      s1 = __builtin_amdgcn_mfma_f32_32x32x16_f16(kf1, qf[c], s1, 0, 0, 0);
    }

    // P = exp2(S') (masked k give S'=0 -> P=1, corrected via cnt at the end)
    float ls = 0.f;
#pragma unroll
    for (int r = 0; r < 16; ++r) {
      s0[r] = exp2f(s0[r]);
      s1[r] = exp2f(s1[r]);
      ls += s0[r];
      ls += s1[r];
    }
    lsum += ls;

    // in-register P -> PV A-fragments (cvt_pkrtz + permlane32_swap)
    f16x8 pa0 = mkpa(s0[0], s0[1], s0[2], s0[3], s0[4], s0[5], s0[6], s0[7]);
    f16x8 pa1 = mkpa(s0[8], s0[9], s0[10], s0[11], s0[12], s0[13], s0[14], s0[15]);
    f16x8 pa2 = mkpa(s1[0], s1[1], s1[2], s1[3], s1[4], s1[5], s1[6], s1[7]);
    f16x8 pa3 = mkpa(s1[8], s1[9], s1[10], s1[11], s1[12], s1[13], s1[14], s1[15]);

#pragma unroll
    for (int kb = 0; kb < 4; ++kb) {
      f16x8 pa = kb == 0 ? pa0 : kb == 1 ? pa1 : (kb == 2 ? pa2 : pa3);
      int gv = ((kb * 2 + hi) ^ (l31 & 7)) << 4;
      f16x8 vf0 = *(const f16x8*)(Vl + l31 * 128 + gv);
      f16x8 vf1 = *(const f16x8*)(Vl + (32 + l31) * 128 + gv);
      o0 = __builtin_amdgcn_mfma_f32_32x32x16_f16(pa, vf0, o0, 0, 0, 0);
      o1 = __builtin_amdgcn_mfma_f32_32x32x16_f16(pa, vf1, o1, 0, 0, 0);
    }
    __syncthreads();
  }

  // l[q=l31] = lsum(hi0) + lsum(hi1) - masked count
  float lq = lsum + __shfl_xor(lsum, 32);
  lq -= cnt[b];
  Llds[w][l31] = lq;
  __syncthreads();

#pragma unroll
  for (int r = 0; r < 16; ++r) {
    int ql = (r & 3) + 8 * (r >> 2) + 4 * hi;
    float inv = 1.0f / Llds[w][ql];
    int qg = qt * 64 + w * 32 + ql;
    size_t base = ((size_t)(b * TT + qg) << 9) + h * 64;
    att[base + l31] = (f16)(o0[r] * inv);
    att[base + 32 + l31] = (f16)(o1[r] * inv);
  }
}

// ---------------- output projection: out = att @ Wo^T + bo (f32) ----------
// 64x128 tile, grid 512 (2 blocks/CU).
__global__ __launch_bounds__(256) void gemm_out(const f16* __restrict__ A,
                                                const f16* __restrict__ W,
                                                const float* __restrict__ bias,
                                                float* __restrict__ out) {
  __shared__ __align__(16) f16 Alds[64 * 64];
  __shared__ __align__(16) f16 Blds[128 * 64];

  const int nt = blockIdx.x & 3;
  const int mt = blockIdx.x >> 2;  // 0..127
  const int tid = threadIdx.x;
  const int w = tid >> 6, lane = tid & 63;
  const int l15 = lane & 15, lg = lane >> 4;
  const int wm = w >> 1, wn = w & 1;

  f32x4 acc[2][4];
#pragma unroll
  for (int mi = 0; mi < 2; ++mi)
#pragma unroll
    for (int nj = 0; nj < 4; ++nj) acc[mi][nj] = {};

  for (int kt = 0; kt < 8; ++kt) {
#pragma unroll
    for (int i = 0; i < 2; ++i) {
      int g = (i * 4 + w) * 64 + lane;  // 0..511
      int row = g >> 3, jj = g & 7;
      int kb = kt * 128 + ((jj ^ (row & 7)) << 4);
      gload_lds16((const char*)A + (size_t)(mt * 64 + row) * 1024 + kb,
                  (char*)Alds + g * 16);
    }
#pragma unroll
    for (int i = 0; i < 4; ++i) {
      int g = (i * 4 + w) * 64 + lane;  // 0..1023
      int row = g >> 3, jj = g & 7;
      int kb = kt * 128 + ((jj ^ (row & 7)) << 4);
      gload_lds16((const char*)W + (size_t)(nt * 128 + row) * 1024 + kb,
                  (char*)Blds + g * 16);
    }
    __syncthreads();

#pragma unroll
    for (int h2 = 0; h2 < 2; ++h2) {
      f16x8 af[2], bf[4];
#pragma unroll
      for (int mi = 0; mi < 2; ++mi) {
        int row = wm * 32 + mi * 16 + l15;
        int bo = (h2 * 64 + (lg << 4)) ^ ((row & 7) << 4);
        af[mi] = *(const f16x8*)((const char*)Alds + row * 128 + bo);
      }
#pragma unroll
      for (int nj = 0; nj < 4; ++nj) {
        int row = wn * 64 + nj * 16 + l15;
        int bo = (h2 * 64 + (lg << 4)) ^ ((row & 7) << 4);
        bf[nj] = *(const f16x8*)((const char*)Blds + row * 128 + bo);
      }
#pragma unroll
      for (int mi = 0; mi < 2; ++mi)
#pragma unroll
        for (int nj = 0; nj < 4; ++nj)
          acc[mi][nj] = __builtin_amdgcn_mfma_f32_16x16x32_f16(
              af[mi], bf[nj], acc[mi][nj], 0, 0, 0);
    }
    __syncthreads();
  }

  const int base_m = mt * 64 + wm * 32;
  const int base_n = nt * 128 + wn * 64;
#pragma unroll
  for (int mi = 0; mi < 2; ++mi)
#pragma unroll
    for (int nj = 0; nj < 4; ++nj) {
      int n = base_n + nj * 16 + l15;
      float bv = bias[n];
#pragma unroll
      for (int r = 0; r < 4; ++r) {
        int m = base_m + mi * 16 + (lg << 2) + r;
        out[(size_t)m * 512 + n] = acc[mi][nj][r] + bv;
      }
    }
}

// ---------------- host launch ----------------
extern "C" void kernel_launch(void* const* d_in, const int* in_sizes, int n_in,
                              void* d_out, int out_size, void* d_ws, size_t ws_size,
                              hipStream_t stream) {
  (void)in_sizes; (void)n_in; (void)out_size; (void)ws_size;
  const float* q = (const float*)d_in[0];
  const float* k = (const float*)d_in[1];
  const float* v = (const float*)d_in[2];
  const int* mask = (const int*)d_in[3];
  const float* Wq = (const float*)d_in[4];
  const float* bq = (const float*)d_in[5];
  const float* Wk = (const float*)d_in[6];
  const float* bk = (const float*)d_in[7];
  const float* Wv = (const float*)d_in[8];
  const float* bv = (const float*)d_in[9];
  const float* Wo = (const float*)d_in[10];
  const float* bo = (const float*)d_in[11];

  char* ws = (char*)d_ws;
  const size_t SZ = (size_t)8192 * 512 * 2;  // 8 MiB per (B,T,D) f16 tensor
  f16* q16 = (f16*)(ws + 0 * SZ);  // q16,k16,v16 contiguous for cvt3
  f16* k16 = (f16*)(ws + 1 * SZ);
  f16* v16 = (f16*)(ws + 2 * SZ);
  f16* qhp = (f16*)(ws + 3 * SZ);
  f16* khp = (f16*)(ws + 4 * SZ);
  f16* vhT = (f16*)(ws + 5 * SZ);
  f16* w16 = (f16*)(ws + 6 * SZ);  // 4 x 512x512 f16, contiguous for cvt4
  f16* wq16 = w16;
  f16* wk16 = w16 + 262144;
  f16* wv16 = w16 + 2 * 262144;
  f16* wo16 = w16 + 3 * 262144;
  float* cntb = (float*)(ws + 6 * SZ + 4 * 262144 * sizeof(f16));
  f16* att = (f16*)(ws + 0 * SZ);  // alias q16 (dead after gemm_qkv)

  cvt3<<<12288, 256, 0, stream>>>(q, k, v, q16);
  cvt4<<<1024, 256, 0, stream>>>(Wq, Wk, Wv, Wo, w16);
  cntk<<<4, 256, 0, stream>>>(mask, cntb);

  // 512^-0.5 * log2(e): fold softmax scale + exp2 conversion into qh
  const float scale = 0.044194173824159216f * 1.4426950408889634f;
  gemm_qkv<<<768, 256, 0, stream>>>(q16, k16, v16, wq16, wk16, wv16, bq, bk, bv,
                                    mask, qhp, khp, vhT, scale);

  attn_k<<<1024, 128, 0, stream>>>(qhp, khp, vhT, cntb, att);

  gemm_out<<<512, 256, 0, stream>>>(att, wo16, bo, (float*)d_out);
}

// Round 4
// 221.165 us; speedup vs baseline: 1.3129x; 1.0743x over previous
//
#include <hip/hip_runtime.h>
#include <stdint.h>

typedef _Float16 f16;
typedef __attribute__((ext_vector_type(4))) _Float16 f16x4;
typedef __attribute__((ext_vector_type(8))) _Float16 f16x8;
typedef __attribute__((ext_vector_type(4))) float f32x4;
typedef __attribute__((ext_vector_type(16))) float f32x16;
typedef __attribute__((ext_vector_type(4))) int int4v;

#define TT 2048
#define HH 8

static __device__ __forceinline__ void gload_lds16(const void* g, void* l) {
  __builtin_amdgcn_global_load_lds((const __attribute__((address_space(1))) void*)g,
                                   (__attribute__((address_space(3))) void*)l, 16, 0, 0);
}

static __device__ __forceinline__ int pkf16(float a, float b) {
  auto h = __builtin_amdgcn_cvt_pkrtz(a, b);  // __fp16 ext_vector(2)
  return __builtin_bit_cast(int, h);
}

static __device__ __forceinline__ void plswap(int& a, int& b) {
  asm("v_permlane32_swap_b32 %0, %1" : "+v"(a), "+v"(b));
}

// Build PV A-fragment (rows=q=lane&31, k-slots=(lane>>5)*8+j) from swapped-QK
// D regs p0..p7 (k = (r&3)+8*(r>>2)+4*hi within a 16-k block).
static __device__ __forceinline__ f16x8 mkpa(float p0, float p1, float p2, float p3,
                                             float p4, float p5, float p6, float p7) {
  int a0 = pkf16(p0, p1), a1 = pkf16(p2, p3);
  int b0 = pkf16(p4, p5), b1 = pkf16(p6, p7);
  plswap(a0, b0);
  plswap(a1, b1);
  int4v w = {a0, a1, b0, b1};
  return __builtin_bit_cast(f16x8, w);
}

// ---------------- converts ----------------
__global__ __launch_bounds__(256) void cvt3(const float* __restrict__ a,
                                            const float* __restrict__ b,
                                            const float* __restrict__ c,
                                            f16* __restrict__ dst) {
  int g = blockIdx.x * 256 + threadIdx.x;  // 3 * 1048576 float4
  int sel = g >> 20, off = g & 1048575;
  const float* s = sel == 0 ? a : sel == 1 ? b : c;
  float4 v = ((const float4*)s)[off];
  f16x4 o = {(_Float16)v.x, (_Float16)v.y, (_Float16)v.z, (_Float16)v.w};
  ((f16x4*)dst)[g] = o;
}

__global__ __launch_bounds__(256) void cvt4(const float* __restrict__ a,
                                            const float* __restrict__ b,
                                            const float* __restrict__ c,
                                            const float* __restrict__ d,
                                            f16* __restrict__ dst) {
  int g = blockIdx.x * 256 + threadIdx.x;  // 4 * 65536 float4
  int sel = g >> 16, off = g & 65535;
  const float* s = sel == 0 ? a : sel == 1 ? b : (sel == 2 ? c : d);
  float4 v = ((const float4*)s)[off];
  f16x4 o = {(_Float16)v.x, (_Float16)v.y, (_Float16)v.z, (_Float16)v.w};
  ((f16x4*)dst)[g] = o;
}

// ---------------- masked-key count per batch ----------------
__global__ __launch_bounds__(256) void cntk(const int* __restrict__ mask,
                                            float* __restrict__ cnt) {
  __shared__ int red[256];
  int b = blockIdx.x, t = threadIdx.x;
  int s = 0;
#pragma unroll
  for (int i = 0; i < 8; ++i) s += (mask[b * 2048 + t * 8 + i] == 0) ? 1 : 0;
  red[t] = s;
  __syncthreads();
  for (int off = 128; off > 0; off >>= 1) {
    if (t < off) red[t] += red[t + off];
    __syncthreads();
  }
  if (t == 0) cnt[b] = (float)red[0];
}

// ---------------- merged q/k/v projection GEMM ----------------
__global__ __launch_bounds__(256) void gemm_qkv(
    const f16* __restrict__ q16, const f16* __restrict__ k16,
    const f16* __restrict__ v16, const f16* __restrict__ wq,
    const f16* __restrict__ wk, const f16* __restrict__ wv,
    const float* __restrict__ bq, const float* __restrict__ bk,
    const float* __restrict__ bv, const int* __restrict__ mask,
    f16* __restrict__ qhp, f16* __restrict__ khp, f16* __restrict__ vhT,
    float scale) {
  __shared__ __align__(16) f16 Alds[128 * 64];
  __shared__ __align__(16) f16 Blds[128 * 64];

  const int prob = blockIdx.x >> 8;
  const int sub = blockIdx.x & 255;
  const int nt = sub & 3, mt = sub >> 2;
  const f16* A = prob == 0 ? q16 : (prob == 1 ? k16 : v16);
  const f16* W = prob == 0 ? wq : (prob == 1 ? wk : wv);
  const float* bias = prob == 0 ? bq : (prob == 1 ? bk : bv);

  const int tid = threadIdx.x;
  const int w = tid >> 6, lane = tid & 63;
  const int l15 = lane & 15, lg = lane >> 4;
  const int wm = w >> 1, wn = w & 1;

  f32x4 acc[4][4];
#pragma unroll
  for (int mi = 0; mi < 4; ++mi)
#pragma unroll
    for (int nj = 0; nj < 4; ++nj) acc[mi][nj] = {};

  for (int kt = 0; kt < 8; ++kt) {
#pragma unroll
    for (int i = 0; i < 4; ++i) {
      int g = (i * 4 + w) * 64 + lane;
      int row = g >> 3, jj = g & 7;
      int kb = kt * 128 + ((jj ^ (row & 7)) << 4);
      gload_lds16((const char*)A + (size_t)(mt * 128 + row) * 1024 + kb,
                  (char*)Alds + g * 16);
      gload_lds16((const char*)W + (size_t)(nt * 128 + row) * 1024 + kb,
                  (char*)Blds + g * 16);
    }
    __syncthreads();

#pragma unroll
    for (int h2 = 0; h2 < 2; ++h2) {
      f16x8 af[4], bf[4];
#pragma unroll
      for (int mi = 0; mi < 4; ++mi) {
        int row = wm * 64 + mi * 16 + l15;
        int bo = (h2 * 64 + (lg << 4)) ^ ((row & 7) << 4);
        af[mi] = *(const f16x8*)((const char*)Alds + row * 128 + bo);
      }
#pragma unroll
      for (int nj = 0; nj < 4; ++nj) {
        int row = wn * 64 + nj * 16 + l15;
        int bo = (h2 * 64 + (lg << 4)) ^ ((row & 7) << 4);
        bf[nj] = *(const f16x8*)((const char*)Blds + row * 128 + bo);
      }
#pragma unroll
      for (int mi = 0; mi < 4; ++mi)
#pragma unroll
        for (int nj = 0; nj < 4; ++nj)
          acc[mi][nj] = __builtin_amdgcn_mfma_f32_16x16x32_f16(
              af[mi], bf[nj], acc[mi][nj], 0, 0, 0);
    }
    __syncthreads();
  }

  const int base_m = mt * 128 + wm * 64;
  const int base_n = nt * 128 + wn * 64;
  float bb[4];
#pragma unroll
  for (int nj = 0; nj < 4; ++nj) bb[nj] = bias[base_n + nj * 16 + l15];

#pragma unroll
  for (int mi = 0; mi < 4; ++mi) {
#pragma unroll
    for (int r = 0; r < 4; ++r) {
      int m = base_m + mi * 16 + (lg << 2) + r;
      int b = m >> 11, t = m & (TT - 1);
      float sc = (prob == 0) ? scale : (mask[(b << 11) + t] ? 1.f : 0.f);
#pragma unroll
      for (int nj = 0; nj < 4; ++nj) {
        int n = base_n + nj * 16 + l15;
        int h = n >> 6, c = n & 63;
        float val = (acc[mi][nj][r] + bb[nj]) * sc;
        if (prob == 2)
          vhT[(((size_t)(b * HH + h) * 64 + c) << 11) + t] = (f16)val;
        else if (prob == 1)
          khp[(((size_t)(b * HH + h) * TT + t) << 6) + c] = (f16)val;
        else
          qhp[(((size_t)(b * HH + h) * TT + t) << 6) + c] = (f16)val;
      }
    }
  }
}

// ---------------- flash attention, 32x32 MFMA, k-split, KBLK=32 ------------
// 4 waves/block: wave w -> q-group (w&1), k-half (w>>1). Each wave: 32 q-rows,
// 32 k-tiles of 32 keys, own double-buffered K/V LDS. Static-max softmax
// (exp2 direct), mask folded into kh/vhT zeroing + cnt[b] correction.
__global__ __launch_bounds__(256, 4) void attn_k(
    const f16* __restrict__ qh, const f16* __restrict__ kh,
    const f16* __restrict__ vhT, const float* __restrict__ cnt,
    f16* __restrict__ att) {
  __shared__ __align__(16) char SMEM[33792];
  // K buffers: SMEM + (hf*2+buf)*4096       (32k x 64c f16, swz (row&7))
  // V buffers: SMEM + 16384 + (hf*2+buf)*4096 (64c x 32t f16, swz (c>>1)&3)
  // reduction R: (float*)SMEM (17152 B, dead buffers)
  // L: (float*)(SMEM + 32768), 2 q-groups x 32 floats

  const int bid = blockIdx.x;
  const int xcd = bid & 7, jj_ = bid >> 3;
  const int bh = xcd * 4 + (jj_ >> 5);  // 4 bh per XCD -> 2MB L2 working set
  const int qt = jj_ & 31;
  const int b = bh >> 3, hd = bh & 7;
  const char* Kp = (const char*)(kh + (size_t)bh * (TT * 64));
  const char* Vp = (const char*)(vhT + (size_t)bh * (64 * TT));
  const f16* Q = qh + (size_t)bh * (TT * 64);

  const int tid = threadIdx.x;
  const int w = tid >> 6, lane = tid & 63;
  const int l31 = lane & 31, hi = lane >> 5;
  const int qg = w & 1, hf = w >> 1;
  const int ht = tid & 127;  // thread index within k-half

  // Q fragments (B operand: col=l31=q, k-slots hi*8+j), dh = 64 -> 4 frags
  const int qrow = qt * 64 + qg * 32 + l31;
  f16x8 qf[4];
#pragma unroll
  for (int c = 0; c < 4; ++c)
    qf[c] = *(const f16x8*)(Q + (size_t)qrow * 64 + c * 16 + hi * 8);

  f32x16 o0 = {}, o1 = {};
  float lsum = 0.f;

#define STAGE(tile, bufp)                                                     \
  {                                                                           \
    const char* Kg = Kp + (size_t)(tile)*4096;                                \
    const char* Vg = Vp + (size_t)(tile)*64;                                  \
    char* Kl = SMEM + (hf * 2 + (bufp)) * 4096;                               \
    char* Vl = SMEM + 16384 + (hf * 2 + (bufp)) * 4096;                       \
    _Pragma("unroll") for (int i2 = 0; i2 < 2; ++i2) {                        \
      int gK = i2 * 128 + ht;                                                 \
      int rK = gK >> 3, jK = gK & 7;                                          \
      gload_lds16(Kg + rK * 128 + ((jK ^ (rK & 7)) << 4), Kl + gK * 16);      \
      int gV = i2 * 128 + ht;                                                 \
      int rV = gV >> 2, jV = gV & 3;                                          \
      gload_lds16(Vg + (size_t)rV * 4096 + ((jV ^ ((rV >> 1) & 3)) << 4),     \
                  Vl + gV * 16);                                              \
    }                                                                         \
  }

  // prologue: stage this half's tile 0 into buf 0
  STAGE(hf * 32, 0);
  __syncthreads();

  for (int it = 0; it < 32; ++it) {
    const int cur = it & 1;
    if (it < 31) STAGE(hf * 32 + it + 1, cur ^ 1);

    const char* Kl = SMEM + (hf * 2 + cur) * 4096;
    const char* Vl = SMEM + 16384 + (hf * 2 + cur) * 4096;

    // S^T = K @ Q^T : A = K rows (32 keys), contraction dh=64
    f32x16 s0 = {};
    __builtin_amdgcn_s_setprio(1);
#pragma unroll
    for (int s = 0; s < 4; ++s) {
      f16x8 af = *(const f16x8*)(Kl + l31 * 128 + (((2 * s + hi) ^ (l31 & 7)) << 4));
      s0 = __builtin_amdgcn_mfma_f32_32x32x16_f16(af, qf[s], s0, 0, 0, 0);
    }
    __builtin_amdgcn_s_setprio(0);

    // P = exp2(S') ; masked keys give S'=0 -> P=1, corrected via cnt
    float ls = 0.f;
#pragma unroll
    for (int r = 0; r < 16; ++r) {
      s0[r] = exp2f(s0[r]);
      ls += s0[r];
    }
    lsum += ls;

    f16x8 pa0 = mkpa(s0[0], s0[1], s0[2], s0[3], s0[4], s0[5], s0[6], s0[7]);
    f16x8 pa1 = mkpa(s0[8], s0[9], s0[10], s0[11], s0[12], s0[13], s0[14], s0[15]);

    // O += P @ V : V-tile rows c (64B), chunk swizzle (c>>1)&3
    __builtin_amdgcn_s_setprio(1);
    {
      int c0 = l31, sw0 = (c0 >> 1) & 3;
      f16x8 vf00 = *(const f16x8*)(Vl + c0 * 64 + (((0 + hi) ^ sw0) << 4));
      f16x8 vf01 = *(const f16x8*)(Vl + c0 * 64 + (((2 + hi) ^ sw0) << 4));
      o0 = __builtin_amdgcn_mfma_f32_32x32x16_f16(pa0, vf00, o0, 0, 0, 0);
      o0 = __builtin_amdgcn_mfma_f32_32x32x16_f16(pa1, vf01, o0, 0, 0, 0);
      int c1 = 32 + l31, sw1 = (c1 >> 1) & 3;
      f16x8 vf10 = *(const f16x8*)(Vl + c1 * 64 + (((0 + hi) ^ sw1) << 4));
      f16x8 vf11 = *(const f16x8*)(Vl + c1 * 64 + (((2 + hi) ^ sw1) << 4));
      o1 = __builtin_amdgcn_mfma_f32_32x32x16_f16(pa0, vf10, o1, 0, 0, 0);
      o1 = __builtin_amdgcn_mfma_f32_32x32x16_f16(pa1, vf11, o1, 0, 0, 0);
    }
    __builtin_amdgcn_s_setprio(0);
    __syncthreads();
  }
#undef STAGE

  // ---- cross-half reduction (K/V buffers are dead now) ----
  float* R = (float*)SMEM;
  float* L = (float*)(SMEM + 32768);
  const int rbase = qg * 2176;
  if (hf == 1) {
#pragma unroll
    for (int rb = 0; rb < 4; ++rb) {
      f32x4 t0 = {o0[4 * rb], o0[4 * rb + 1], o0[4 * rb + 2], o0[4 * rb + 3]};
      *(f32x4*)(R + rbase + rb * 256 + lane * 4) = t0;
      f32x4 t1 = {o1[4 * rb], o1[4 * rb + 1], o1[4 * rb + 2], o1[4 * rb + 3]};
      *(f32x4*)(R + rbase + 1024 + rb * 256 + lane * 4) = t1;
    }
    R[rbase + 2048 + lane] = lsum;
  }
  __syncthreads();
  if (hf == 0) {
#pragma unroll
    for (int rb = 0; rb < 4; ++rb) {
      f32x4 t0 = *(const f32x4*)(R + rbase + rb * 256 + lane * 4);
      f32x4 t1 = *(const f32x4*)(R + rbase + 1024 + rb * 256 + lane * 4);
#pragma unroll
      for (int q = 0; q < 4; ++q) {
        o0[4 * rb + q] += t0[q];
        o1[4 * rb + q] += t1[q];
      }
    }
    lsum += R[rbase + 2048 + lane];
    float lq = lsum + __shfl_xor(lsum, 32);
    lq -= cnt[b];
    L[qg * 32 + l31] = lq;  // wave-synchronous write/read

#pragma unroll
    for (int r = 0; r < 16; ++r) {
      int qloc = (r & 3) + 8 * (r >> 2) + 4 * hi;
      float inv = 1.0f / L[qg * 32 + qloc];
      int qgrow = qt * 64 + qg * 32 + qloc;
      size_t ob = ((size_t)(b * TT + qgrow) << 9) + hd * 64;
      att[ob + l31] = (f16)(o0[r] * inv);
      att[ob + 32 + l31] = (f16)(o1[r] * inv);
    }
  }
}

// ---------------- output projection: out = att @ Wo^T + bo (f32) ----------
__global__ __launch_bounds__(256) void gemm_out(const f16* __restrict__ A,
                                                const f16* __restrict__ W,
                                                const float* __restrict__ bias,
                                                float* __restrict__ out) {
  __shared__ __align__(16) f16 Alds[64 * 64];
  __shared__ __align__(16) f16 Blds[128 * 64];

  const int nt = blockIdx.x & 3;
  const int mt = blockIdx.x >> 2;  // 0..127
  const int tid = threadIdx.x;
  const int w = tid >> 6, lane = tid & 63;
  const int l15 = lane & 15, lg = lane >> 4;
  const int wm = w >> 1, wn = w & 1;

  f32x4 acc[2][4];
#pragma unroll
  for (int mi = 0; mi < 2; ++mi)
#pragma unroll
    for (int nj = 0; nj < 4; ++nj) acc[mi][nj] = {};

  for (int kt = 0; kt < 8; ++kt) {
#pragma unroll
    for (int i = 0; i < 2; ++i) {
      int g = (i * 4 + w) * 64 + lane;  // 0..511
      int row = g >> 3, jj = g & 7;
      int kb = kt * 128 + ((jj ^ (row & 7)) << 4);
      gload_lds16((const char*)A + (size_t)(mt * 64 + row) * 1024 + kb,
                  (char*)Alds + g * 16);
    }
#pragma unroll
    for (int i = 0; i < 4; ++i) {
      int g = (i * 4 + w) * 64 + lane;  // 0..1023
      int row = g >> 3, jj = g & 7;
      int kb = kt * 128 + ((jj ^ (row & 7)) << 4);
      gload_lds16((const char*)W + (size_t)(nt * 128 + row) * 1024 + kb,
                  (char*)Blds + g * 16);
    }
    __syncthreads();

#pragma unroll
    for (int h2 = 0; h2 < 2; ++h2) {
      f16x8 af[2], bf[4];
#pragma unroll
      for (int mi = 0; mi < 2; ++mi) {
        int row = wm * 32 + mi * 16 + l15;
        int bo = (h2 * 64 + (lg << 4)) ^ ((row & 7) << 4);
        af[mi] = *(const f16x8*)((const char*)Alds + row * 128 + bo);
      }
#pragma unroll
      for (int nj = 0; nj < 4; ++nj) {
        int row = wn * 64 + nj * 16 + l15;
        int bo = (h2 * 64 + (lg << 4)) ^ ((row & 7) << 4);
        bf[nj] = *(const f16x8*)((const char*)Blds + row * 128 + bo);
      }
#pragma unroll
      for (int mi = 0; mi < 2; ++mi)
#pragma unroll
        for (int nj = 0; nj < 4; ++nj)
          acc[mi][nj] = __builtin_amdgcn_mfma_f32_16x16x32_f16(
              af[mi], bf[nj], acc[mi][nj], 0, 0, 0);
    }
    __syncthreads();
  }

  const int base_m = mt * 64 + wm * 32;
  const int base_n = nt * 128 + wn * 64;
#pragma unroll
  for (int mi = 0; mi < 2; ++mi)
#pragma unroll
    for (int nj = 0; nj < 4; ++nj) {
      int n = base_n + nj * 16 + l15;
      float bv = bias[n];
#pragma unroll
      for (int r = 0; r < 4; ++r) {
        int m = base_m + mi * 16 + (lg << 2) + r;
        out[(size_t)m * 512 + n] = acc[mi][nj][r] + bv;
      }
    }
}

// ---------------- host launch ----------------
extern "C" void kernel_launch(void* const* d_in, const int* in_sizes, int n_in,
                              void* d_out, int out_size, void* d_ws, size_t ws_size,
                              hipStream_t stream) {
  (void)in_sizes; (void)n_in; (void)out_size; (void)ws_size;
  const float* q = (const float*)d_in[0];
  const float* k = (const float*)d_in[1];
  const float* v = (const float*)d_in[2];
  const int* mask = (const int*)d_in[3];
  const float* Wq = (const float*)d_in[4];
  const float* bq = (const float*)d_in[5];
  const float* Wk = (const float*)d_in[6];
  const float* bk = (const float*)d_in[7];
  const float* Wv = (const float*)d_in[8];
  const float* bv = (const float*)d_in[9];
  const float* Wo = (const float*)d_in[10];
  const float* bo = (const float*)d_in[11];

  char* ws = (char*)d_ws;
  const size_t SZ = (size_t)8192 * 512 * 2;  // 8 MiB per (B,T,D) f16 tensor
  f16* q16 = (f16*)(ws + 0 * SZ);  // q16,k16,v16 contiguous for cvt3
  f16* k16 = (f16*)(ws + 1 * SZ);
  f16* v16 = (f16*)(ws + 2 * SZ);
  f16* qhp = (f16*)(ws + 3 * SZ);
  f16* khp = (f16*)(ws + 4 * SZ);
  f16* vhT = (f16*)(ws + 5 * SZ);
  f16* w16 = (f16*)(ws + 6 * SZ);  // 4 x 512x512 f16, contiguous for cvt4
  f16* wq16 = w16;
  f16* wk16 = w16 + 262144;
  f16* wv16 = w16 + 2 * 262144;
  f16* wo16 = w16 + 3 * 262144;
  float* cntb = (float*)(ws + 6 * SZ + 4 * 262144 * sizeof(f16));
  f16* att = (f16*)(ws + 0 * SZ);  // alias q16 (dead after gemm_qkv)

  cvt3<<<12288, 256, 0, stream>>>(q, k, v, q16);
  cvt4<<<1024, 256, 0, stream>>>(Wq, Wk, Wv, Wo, w16);
  cntk<<<4, 256, 0, stream>>>(mask, cntb);

  // 512^-0.5 * log2(e): fold softmax scale + exp2 conversion into qh
  const float scale = 0.044194173824159216f * 1.4426950408889634f;
  gemm_qkv<<<768, 256, 0, stream>>>(q16, k16, v16, wq16, wk16, wv16, bq, bk, bv,
                                    mask, qhp, khp, vhT, scale);

  attn_k<<<1024, 256, 0, stream>>>(qhp, khp, vhT, cntb, att);

  gemm_out<<<512, 256, 0, stream>>>(att, wo16, bo, (float*)d_out);
}

// Round 5
// 216.142 us; speedup vs baseline: 1.3435x; 1.0232x over previous
//
#include <hip/hip_runtime.h>
#include <stdint.h>

typedef _Float16 f16;
typedef __attribute__((ext_vector_type(4))) _Float16 f16x4;
typedef __attribute__((ext_vector_type(8))) _Float16 f16x8;
typedef __attribute__((ext_vector_type(4))) float f32x4;
typedef __attribute__((ext_vector_type(16))) float f32x16;
typedef __attribute__((ext_vector_type(4))) int int4v;

#define TT 2048
#define HH 8

static __device__ __forceinline__ void gload_lds16(const void* g, void* l) {
  __builtin_amdgcn_global_load_lds((const __attribute__((address_space(1))) void*)g,
                                   (__attribute__((address_space(3))) void*)l, 16, 0, 0);
}

static __device__ __forceinline__ int pkf16(float a, float b) {
  auto h = __builtin_amdgcn_cvt_pkrtz(a, b);  // __fp16 ext_vector(2)
  return __builtin_bit_cast(int, h);
}

static __device__ __forceinline__ void plswap(int& a, int& b) {
  asm("v_permlane32_swap_b32 %0, %1" : "+v"(a), "+v"(b));
}

// Build PV A-fragment (rows=q=lane&31, k-slots=(lane>>5)*8+j) from swapped-QK
// D regs p0..p7 (k = (r&3)+8*(r>>2)+4*hi within a 16-k block).
static __device__ __forceinline__ f16x8 mkpa(float p0, float p1, float p2, float p3,
                                             float p4, float p5, float p6, float p7) {
  int a0 = pkf16(p0, p1), a1 = pkf16(p2, p3);
  int b0 = pkf16(p4, p5), b1 = pkf16(p6, p7);
  plswap(a0, b0);
  plswap(a1, b1);
  int4v w = {a0, a1, b0, b1};
  return __builtin_bit_cast(f16x8, w);
}

// ---------------- converts ----------------
__global__ __launch_bounds__(256) void cvt3(const float* __restrict__ a,
                                            const float* __restrict__ b,
                                            const float* __restrict__ c,
                                            f16* __restrict__ dst) {
  int g = blockIdx.x * 256 + threadIdx.x;  // 3 * 1048576 float4
  int sel = g >> 20, off = g & 1048575;
  const float* s = sel == 0 ? a : sel == 1 ? b : c;
  float4 v = ((const float4*)s)[off];
  f16x4 o = {(_Float16)v.x, (_Float16)v.y, (_Float16)v.z, (_Float16)v.w};
  ((f16x4*)dst)[g] = o;
}

__global__ __launch_bounds__(256) void cvt4(const float* __restrict__ a,
                                            const float* __restrict__ b,
                                            const float* __restrict__ c,
                                            const float* __restrict__ d,
                                            f16* __restrict__ dst) {
  int g = blockIdx.x * 256 + threadIdx.x;  // 4 * 65536 float4
  int sel = g >> 16, off = g & 65535;
  const float* s = sel == 0 ? a : sel == 1 ? b : (sel == 2 ? c : d);
  float4 v = ((const float4*)s)[off];
  f16x4 o = {(_Float16)v.x, (_Float16)v.y, (_Float16)v.z, (_Float16)v.w};
  ((f16x4*)dst)[g] = o;
}

// ---------------- masked-key count per batch ----------------
__global__ __launch_bounds__(256) void cntk(const int* __restrict__ mask,
                                            float* __restrict__ cnt) {
  __shared__ int red[256];
  int b = blockIdx.x, t = threadIdx.x;
  int s = 0;
#pragma unroll
  for (int i = 0; i < 8; ++i) s += (mask[b * 2048 + t * 8 + i] == 0) ? 1 : 0;
  red[t] = s;
  __syncthreads();
  for (int off = 128; off > 0; off >>= 1) {
    if (t < off) red[t] += red[t + off];
    __syncthreads();
  }
  if (t == 0) cnt[b] = (float)red[0];
}

// ---------------- merged q/k/v projection GEMM, 64x128 tiles --------------
// grid 1536 (XCD-chunked swizzle): prob 0=q,1=k,2=v; 2 waves/block.
// prob0: qh (B,H,T,64) * scale ; prob1: kh (B,H,T,64) masked-zero ;
// prob2: vh (B,H,T,64) masked-zero (transposed later by vtr).
__global__ __launch_bounds__(128, 3) void gemm_qkv(
    const f16* __restrict__ q16, const f16* __restrict__ k16,
    const f16* __restrict__ v16, const f16* __restrict__ wq,
    const f16* __restrict__ wk, const f16* __restrict__ wv,
    const float* __restrict__ bq, const float* __restrict__ bk,
    const float* __restrict__ bv, const int* __restrict__ mask,
    f16* __restrict__ qhp, f16* __restrict__ khp, f16* __restrict__ vh,
    float scale) {
  __shared__ __align__(16) f16 Alds[64 * 64];    // 8 KB
  __shared__ __align__(16) f16 Blds[128 * 64];   // 16 KB

  // XCD-chunked swizzle: each XCD owns 192 contiguous logical blocks
  const int raw = blockIdx.x;
  const int bid = (raw & 7) * 192 + (raw >> 3);
  const int prob = bid / 512;
  const int sub = bid - prob * 512;
  const int mt = sub >> 2, nt = sub & 3;  // mt 0..127 (64 rows), nt 0..3 (128 cols)

  const f16* A = prob == 0 ? q16 : (prob == 1 ? k16 : v16);
  const f16* W = prob == 0 ? wq : (prob == 1 ? wk : wv);
  const float* bias = prob == 0 ? bq : (prob == 1 ? bk : bv);
  f16* outp = prob == 0 ? qhp : (prob == 1 ? khp : vh);

  const int tid = threadIdx.x;
  const int w = tid >> 6, lane = tid & 63;
  const int l15 = lane & 15, lg = lane >> 4;

  f32x4 acc[2][8];
#pragma unroll
  for (int mi = 0; mi < 2; ++mi)
#pragma unroll
    for (int nj = 0; nj < 8; ++nj) acc[mi][nj] = {};

  for (int kt = 0; kt < 8; ++kt) {
    // stage A (64x64 f16 = 512 granules) and W (128x64 = 1024 granules)
#pragma unroll
    for (int i = 0; i < 4; ++i) {
      int g = i * 128 + tid;
      int row = g >> 3, jj = g & 7;
      int kb = kt * 128 + ((jj ^ (row & 7)) << 4);
      gload_lds16((const char*)A + (size_t)(mt * 64 + row) * 1024 + kb,
                  (char*)Alds + g * 16);
    }
#pragma unroll
    for (int i = 0; i < 8; ++i) {
      int g = i * 128 + tid;
      int row = g >> 3, jj = g & 7;
      int kb = kt * 128 + ((jj ^ (row & 7)) << 4);
      gload_lds16((const char*)W + (size_t)(nt * 128 + row) * 1024 + kb,
                  (char*)Blds + g * 16);
    }
    __syncthreads();

#pragma unroll
    for (int h2 = 0; h2 < 2; ++h2) {
      f16x8 af[2], bf[8];
#pragma unroll
      for (int mi = 0; mi < 2; ++mi) {
        int row = w * 32 + mi * 16 + l15;
        int bo = (h2 * 64 + (lg << 4)) ^ ((row & 7) << 4);
        af[mi] = *(const f16x8*)((const char*)Alds + row * 128 + bo);
      }
#pragma unroll
      for (int nj = 0; nj < 8; ++nj) {
        int row = nj * 16 + l15;
        int bo = (h2 * 64 + (lg << 4)) ^ ((row & 7) << 4);
        bf[nj] = *(const f16x8*)((const char*)Blds + row * 128 + bo);
      }
#pragma unroll
      for (int mi = 0; mi < 2; ++mi)
#pragma unroll
        for (int nj = 0; nj < 8; ++nj)
          acc[mi][nj] = __builtin_amdgcn_mfma_f32_16x16x32_f16(
              af[mi], bf[nj], acc[mi][nj], 0, 0, 0);
    }
    __syncthreads();
  }

  const int base_m = mt * 64 + w * 32;
  const int base_n = nt * 128;
  float bb[8];
#pragma unroll
  for (int nj = 0; nj < 8; ++nj) bb[nj] = bias[base_n + nj * 16 + l15];

#pragma unroll
  for (int mi = 0; mi < 2; ++mi) {
#pragma unroll
    for (int r = 0; r < 4; ++r) {
      int m = base_m + mi * 16 + (lg << 2) + r;
      int b = m >> 11, t = m & (TT - 1);
      float sc = (prob == 0) ? scale : (mask[(b << 11) + t] ? 1.f : 0.f);
#pragma unroll
      for (int nj = 0; nj < 8; ++nj) {
        int n = base_n + nj * 16 + l15;
        int h = n >> 6, c = n & 63;
        float val = (acc[mi][nj][r] + bb[nj]) * sc;
        outp[(((size_t)(b * HH + h) * TT + t) << 6) + c] = (f16)val;
      }
    }
  }
}

// ---------------- V transpose: vh (B,H,T,64) -> vhT (B,H,64,T) ------------
// Reads 128B-coalesced rows (lane = c), writes f16x8 chunks along t.
__global__ __launch_bounds__(256) void vtr(const f16* __restrict__ vh,
                                           f16* __restrict__ vhT) {
  const int bid = blockIdx.x;       // 1024 = 32 bh x 32 t-blocks
  const int bh = bid >> 5, tb = bid & 31;
  const f16* src = vh + (size_t)bh * (TT * 64) + tb * 64 * 64;
  f16* dst = vhT + (size_t)bh * (64 * TT) + tb * 64;
  const int c = threadIdx.x & 63, oct = threadIdx.x >> 6;  // oct 0..3
#pragma unroll
  for (int o2 = 0; o2 < 2; ++o2) {
    int toct = oct + o2 * 4;  // 0..7
    f16x8 tmp;
#pragma unroll
    for (int i = 0; i < 8; ++i) tmp[i] = src[(toct * 8 + i) * 64 + c];
    *(f16x8*)(dst + (size_t)c * TT + toct * 8) = tmp;
  }
}

// ---------------- flash attention, 32x32 MFMA, k-split, KBLK=32 ------------
__global__ __launch_bounds__(256, 4) void attn_k(
    const f16* __restrict__ qh, const f16* __restrict__ kh,
    const f16* __restrict__ vhT, const float* __restrict__ cnt,
    f16* __restrict__ att) {
  __shared__ __align__(16) char SMEM[33792];

  const int bid = blockIdx.x;
  const int xcd = bid & 7, jj_ = bid >> 3;
  const int bh = xcd * 4 + (jj_ >> 5);  // 4 bh per XCD -> 2MB L2 working set
  const int qt = jj_ & 31;
  const int b = bh >> 3, hd = bh & 7;
  const char* Kp = (const char*)(kh + (size_t)bh * (TT * 64));
  const char* Vp = (const char*)(vhT + (size_t)bh * (64 * TT));
  const f16* Q = qh + (size_t)bh * (TT * 64);

  const int tid = threadIdx.x;
  const int w = tid >> 6, lane = tid & 63;
  const int l31 = lane & 31, hi = lane >> 5;
  const int qg = w & 1, hf = w >> 1;
  const int ht = tid & 127;

  const int qrow = qt * 64 + qg * 32 + l31;
  f16x8 qf[4];
#pragma unroll
  for (int c = 0; c < 4; ++c)
    qf[c] = *(const f16x8*)(Q + (size_t)qrow * 64 + c * 16 + hi * 8);

  f32x16 o0 = {}, o1 = {};
  float lsum = 0.f;

#define STAGE(tile, bufp)                                                     \
  {                                                                           \
    const char* Kg = Kp + (size_t)(tile)*4096;                                \
    const char* Vg = Vp + (size_t)(tile)*64;                                  \
    char* Kl = SMEM + (hf * 2 + (bufp)) * 4096;                               \
    char* Vl = SMEM + 16384 + (hf * 2 + (bufp)) * 4096;                       \
    _Pragma("unroll") for (int i2 = 0; i2 < 2; ++i2) {                        \
      int gK = i2 * 128 + ht;                                                 \
      int rK = gK >> 3, jK = gK & 7;                                          \
      gload_lds16(Kg + rK * 128 + ((jK ^ (rK & 7)) << 4), Kl + gK * 16);      \
      int gV = i2 * 128 + ht;                                                 \
      int rV = gV >> 2, jV = gV & 3;                                          \
      gload_lds16(Vg + (size_t)rV * 4096 + ((jV ^ ((rV >> 1) & 3)) << 4),     \
                  Vl + gV * 16);                                              \
    }                                                                         \
  }

  STAGE(hf * 32, 0);
  __syncthreads();

  for (int it = 0; it < 32; ++it) {
    const int cur = it & 1;
    if (it < 31) STAGE(hf * 32 + it + 1, cur ^ 1);

    const char* Kl = SMEM + (hf * 2 + cur) * 4096;
    const char* Vl = SMEM + 16384 + (hf * 2 + cur) * 4096;

    f32x16 s0 = {};
    __builtin_amdgcn_s_setprio(1);
#pragma unroll
    for (int s = 0; s < 4; ++s) {
      f16x8 af = *(const f16x8*)(Kl + l31 * 128 + (((2 * s + hi) ^ (l31 & 7)) << 4));
      s0 = __builtin_amdgcn_mfma_f32_32x32x16_f16(af, qf[s], s0, 0, 0, 0);
    }
    __builtin_amdgcn_s_setprio(0);

    float ls = 0.f;
#pragma unroll
    for (int r = 0; r < 16; ++r) {
      s0[r] = exp2f(s0[r]);
      ls += s0[r];
    }
    lsum += ls;

    f16x8 pa0 = mkpa(s0[0], s0[1], s0[2], s0[3], s0[4], s0[5], s0[6], s0[7]);
    f16x8 pa1 = mkpa(s0[8], s0[9], s0[10], s0[11], s0[12], s0[13], s0[14], s0[15]);

    __builtin_amdgcn_s_setprio(1);
    {
      int c0 = l31, sw0 = (c0 >> 1) & 3;
      f16x8 vf00 = *(const f16x8*)(Vl + c0 * 64 + (((0 + hi) ^ sw0) << 4));
      f16x8 vf01 = *(const f16x8*)(Vl + c0 * 64 + (((2 + hi) ^ sw0) << 4));
      o0 = __builtin_amdgcn_mfma_f32_32x32x16_f16(pa0, vf00, o0, 0, 0, 0);
      o0 = __builtin_amdgcn_mfma_f32_32x32x16_f16(pa1, vf01, o0, 0, 0, 0);
      int c1 = 32 + l31, sw1 = (c1 >> 1) & 3;
      f16x8 vf10 = *(const f16x8*)(Vl + c1 * 64 + (((0 + hi) ^ sw1) << 4));
      f16x8 vf11 = *(const f16x8*)(Vl + c1 * 64 + (((2 + hi) ^ sw1) << 4));
      o1 = __builtin_amdgcn_mfma_f32_32x32x16_f16(pa0, vf10, o1, 0, 0, 0);
      o1 = __builtin_amdgcn_mfma_f32_32x32x16_f16(pa1, vf11, o1, 0, 0, 0);
    }
    __builtin_amdgcn_s_setprio(0);
    __syncthreads();
  }
#undef STAGE

  float* R = (float*)SMEM;
  float* L = (float*)(SMEM + 32768);
  const int rbase = qg * 2176;
  if (hf == 1) {
#pragma unroll
    for (int rb = 0; rb < 4; ++rb) {
      f32x4 t0 = {o0[4 * rb], o0[4 * rb + 1], o0[4 * rb + 2], o0[4 * rb + 3]};
      *(f32x4*)(R + rbase + rb * 256 + lane * 4) = t0;
      f32x4 t1 = {o1[4 * rb], o1[4 * rb + 1], o1[4 * rb + 2], o1[4 * rb + 3]};
      *(f32x4*)(R + rbase + 1024 + rb * 256 + lane * 4) = t1;
    }
    R[rbase + 2048 + lane] = lsum;
  }
  __syncthreads();
  if (hf == 0) {
#pragma unroll
    for (int rb = 0; rb < 4; ++rb) {
      f32x4 t0 = *(const f32x4*)(R + rbase + rb * 256 + lane * 4);
      f32x4 t1 = *(const f32x4*)(R + rbase + 1024 + rb * 256 + lane * 4);
#pragma unroll
      for (int q = 0; q < 4; ++q) {
        o0[4 * rb + q] += t0[q];
        o1[4 * rb + q] += t1[q];
      }
    }
    lsum += R[rbase + 2048 + lane];
    float lq = lsum + __shfl_xor(lsum, 32);
    lq -= cnt[b];
    L[qg * 32 + l31] = lq;

#pragma unroll
    for (int r = 0; r < 16; ++r) {
      int qloc = (r & 3) + 8 * (r >> 2) + 4 * hi;
      float inv = 1.0f / L[qg * 32 + qloc];
      int qgrow = qt * 64 + qg * 32 + qloc;
      size_t ob = ((size_t)(b * TT + qgrow) << 9) + hd * 64;
      att[ob + l31] = (f16)(o0[r] * inv);
      att[ob + 32 + l31] = (f16)(o1[r] * inv);
    }
  }
}

// ---------------- output projection: out = att @ Wo^T + bo (f32) ----------
__global__ __launch_bounds__(256) void gemm_out(const f16* __restrict__ A,
                                                const f16* __restrict__ W,
                                                const float* __restrict__ bias,
                                                float* __restrict__ out) {
  __shared__ __align__(16) f16 Alds[64 * 64];
  __shared__ __align__(16) f16 Blds[128 * 64];

  const int nt = blockIdx.x & 3;
  const int mt = blockIdx.x >> 2;  // 0..127
  const int tid = threadIdx.x;
  const int w = tid >> 6, lane = tid & 63;
  const int l15 = lane & 15, lg = lane >> 4;
  const int wm = w >> 1, wn = w & 1;

  f32x4 acc[2][4];
#pragma unroll
  for (int mi = 0; mi < 2; ++mi)
#pragma unroll
    for (int nj = 0; nj < 4; ++nj) acc[mi][nj] = {};

  for (int kt = 0; kt < 8; ++kt) {
#pragma unroll
    for (int i = 0; i < 2; ++i) {
      int g = (i * 4 + w) * 64 + lane;  // 0..511
      int row = g >> 3, jj = g & 7;
      int kb = kt * 128 + ((jj ^ (row & 7)) << 4);
      gload_lds16((const char*)A + (size_t)(mt * 64 + row) * 1024 + kb,
                  (char*)Alds + g * 16);
    }
#pragma unroll
    for (int i = 0; i < 4; ++i) {
      int g = (i * 4 + w) * 64 + lane;  // 0..1023
      int row = g >> 3, jj = g & 7;
      int kb = kt * 128 + ((jj ^ (row & 7)) << 4);
      gload_lds16((const char*)W + (size_t)(nt * 128 + row) * 1024 + kb,
                  (char*)Blds + g * 16);
    }
    __syncthreads();

#pragma unroll
    for (int h2 = 0; h2 < 2; ++h2) {
      f16x8 af[2], bf[4];
#pragma unroll
      for (int mi = 0; mi < 2; ++mi) {
        int row = wm * 32 + mi * 16 + l15;
        int bo = (h2 * 64 + (lg << 4)) ^ ((row & 7) << 4);
        af[mi] = *(const f16x8*)((const char*)Alds + row * 128 + bo);
      }
#pragma unroll
      for (int nj = 0; nj < 4; ++nj) {
        int row = wn * 64 + nj * 16 + l15;
        int bo = (h2 * 64 + (lg << 4)) ^ ((row & 7) << 4);
        bf[nj] = *(const f16x8*)((const char*)Blds + row * 128 + bo);
      }
#pragma unroll
      for (int mi = 0; mi < 2; ++mi)
#pragma unroll
        for (int nj = 0; nj < 4; ++nj)
          acc[mi][nj] = __builtin_amdgcn_mfma_f32_16x16x32_f16(
              af[mi], bf[nj], acc[mi][nj], 0, 0, 0);
    }
    __syncthreads();
  }

  const int base_m = mt * 64 + wm * 32;
  const int base_n = nt * 128 + wn * 64;
#pragma unroll
  for (int mi = 0; mi < 2; ++mi)
#pragma unroll
    for (int nj = 0; nj < 4; ++nj) {
      int n = base_n + nj * 16 + l15;
      float bv = bias[n];
#pragma unroll
      for (int r = 0; r < 4; ++r) {
        int m = base_m + mi * 16 + (lg << 2) + r;
        out[(size_t)m * 512 + n] = acc[mi][nj][r] + bv;
      }
    }
}

// ---------------- host launch ----------------
extern "C" void kernel_launch(void* const* d_in, const int* in_sizes, int n_in,
                              void* d_out, int out_size, void* d_ws, size_t ws_size,
                              hipStream_t stream) {
  (void)in_sizes; (void)n_in; (void)out_size; (void)ws_size;
  const float* q = (const float*)d_in[0];
  const float* k = (const float*)d_in[1];
  const float* v = (const float*)d_in[2];
  const int* mask = (const int*)d_in[3];
  const float* Wq = (const float*)d_in[4];
  const float* bq = (const float*)d_in[5];
  const float* Wk = (const float*)d_in[6];
  const float* bk = (const float*)d_in[7];
  const float* Wv = (const float*)d_in[8];
  const float* bv = (const float*)d_in[9];
  const float* Wo = (const float*)d_in[10];
  const float* bo = (const float*)d_in[11];

  char* ws = (char*)d_ws;
  const size_t SZ = (size_t)8192 * 512 * 2;  // 8 MiB per (B,T,D) f16 tensor
  f16* q16 = (f16*)(ws + 0 * SZ);  // q16,k16,v16 contiguous for cvt3
  f16* k16 = (f16*)(ws + 1 * SZ);
  f16* v16 = (f16*)(ws + 2 * SZ);
  f16* qhp = (f16*)(ws + 3 * SZ);
  f16* khp = (f16*)(ws + 4 * SZ);
  f16* vhT = (f16*)(ws + 5 * SZ);
  f16* vh  = (f16*)(ws + 6 * SZ);
  f16* w16 = (f16*)(ws + 7 * SZ);  // 4 x 512x512 f16, contiguous for cvt4
  f16* wq16 = w16;
  f16* wk16 = w16 + 262144;
  f16* wv16 = w16 + 2 * 262144;
  f16* wo16 = w16 + 3 * 262144;
  float* cntb = (float*)(ws + 7 * SZ + 4 * 262144 * sizeof(f16));
  f16* att = (f16*)(ws + 0 * SZ);  // alias q16 (dead after gemm_qkv)

  cvt3<<<12288, 256, 0, stream>>>(q, k, v, q16);
  cvt4<<<1024, 256, 0, stream>>>(Wq, Wk, Wv, Wo, w16);
  cntk<<<4, 256, 0, stream>>>(mask, cntb);

  // 512^-0.5 * log2(e): fold softmax scale + exp2 conversion into qh
  const float scale = 0.044194173824159216f * 1.4426950408889634f;
  gemm_qkv<<<1536, 128, 0, stream>>>(q16, k16, v16, wq16, wk16, wv16, bq, bk, bv,
                                     mask, qhp, khp, vh, scale);
  vtr<<<1024, 256, 0, stream>>>(vh, vhT);

  attn_k<<<1024, 256, 0, stream>>>(qhp, khp, vhT, cntb, att);

  gemm_out<<<512, 256, 0, stream>>>(att, wo16, bo, (float*)d_out);
}

// Round 6
// 204.433 us; speedup vs baseline: 1.4204x; 1.0573x over previous
//
#include <hip/hip_runtime.h>
#include <stdint.h>

typedef _Float16 f16;
typedef __attribute__((ext_vector_type(4))) _Float16 f16x4;
typedef __attribute__((ext_vector_type(8))) _Float16 f16x8;
typedef __attribute__((ext_vector_type(4))) float f32x4;
typedef __attribute__((ext_vector_type(16))) float f32x16;
typedef __attribute__((ext_vector_type(4))) int int4v;

#define TT 2048
#define HH 8

static __device__ __forceinline__ void gload_lds16(const void* g, void* l) {
  __builtin_amdgcn_global_load_lds((const __attribute__((address_space(1))) void*)g,
                                   (__attribute__((address_space(3))) void*)l, 16, 0, 0);
}

static __device__ __forceinline__ int pkf16(float a, float b) {
  auto h = __builtin_amdgcn_cvt_pkrtz(a, b);  // __fp16 ext_vector(2)
  return __builtin_bit_cast(int, h);
}

static __device__ __forceinline__ void plswap(int& a, int& b) {
  asm("v_permlane32_swap_b32 %0, %1" : "+v"(a), "+v"(b));
}

// Build PV A-fragment (rows=q=lane&31, k-slots=(lane>>5)*8+j) from swapped-QK
// D regs p0..p7 (k = (r&3)+8*(r>>2)+4*hi within a 16-k block).
static __device__ __forceinline__ f16x8 mkpa(float p0, float p1, float p2, float p3,
                                             float p4, float p5, float p6, float p7) {
  int a0 = pkf16(p0, p1), a1 = pkf16(p2, p3);
  int b0 = pkf16(p4, p5), b1 = pkf16(p6, p7);
  plswap(a0, b0);
  plswap(a1, b1);
  int4v w = {a0, a1, b0, b1};
  return __builtin_bit_cast(f16x8, w);
}

// ---------------- merged prep: cvt q/k/v, cvt weights, mask count ----------
// grid 13316 x 256:
//   bid < 12288        : cvt q,k,v (f32->f16), 3 x 1048576 float4
//   12288 <= bid <13312: cvt Wq,Wk,Wv,Wo, 4 x 65536 float4
//   bid >= 13312       : per-batch masked-key count (4 blocks)
__global__ __launch_bounds__(256) void prep(
    const float* __restrict__ q, const float* __restrict__ k,
    const float* __restrict__ v, const float* __restrict__ Wq,
    const float* __restrict__ Wk, const float* __restrict__ Wv,
    const float* __restrict__ Wo, const int* __restrict__ mask,
    f16* __restrict__ qkv16, f16* __restrict__ w16, float* __restrict__ cnt) {
  const int bid = blockIdx.x;
  if (bid < 12288) {
    int g = bid * 256 + threadIdx.x;
    int sel = g >> 20, off = g & 1048575;
    const float* s = sel == 0 ? q : sel == 1 ? k : v;
    float4 val = ((const float4*)s)[off];
    f16x4 o = {(_Float16)val.x, (_Float16)val.y, (_Float16)val.z, (_Float16)val.w};
    ((f16x4*)qkv16)[g] = o;
  } else if (bid < 13312) {
    int g = (bid - 12288) * 256 + threadIdx.x;
    int sel = g >> 16, off = g & 65535;
    const float* s = sel == 0 ? Wq : sel == 1 ? Wk : (sel == 2 ? Wv : Wo);
    float4 val = ((const float4*)s)[off];
    f16x4 o = {(_Float16)val.x, (_Float16)val.y, (_Float16)val.z, (_Float16)val.w};
    ((f16x4*)w16)[g] = o;
  } else {
    __shared__ int red[256];
    int b = bid - 13312, t = threadIdx.x;
    int s = 0;
#pragma unroll
    for (int i = 0; i < 8; ++i) s += (mask[b * 2048 + t * 8 + i] == 0) ? 1 : 0;
    red[t] = s;
    __syncthreads();
    for (int off = 128; off > 0; off >>= 1) {
      if (t < off) red[t] += red[t + off];
      __syncthreads();
    }
    if (t == 0) cnt[b] = (float)red[0];
  }
}

// ---------------- merged q/k/v projection GEMM, 64x128 tiles --------------
// grid 1536 (XCD-chunked swizzle): prob 0=q,1=k,2=v; 2 waves/block.
// prob0: qh (B,H,T,64) * scale ; prob1: kh (B,H,T,64) masked-zero ;
// prob2: vhT (B,H,64,T) masked-zero, via in-block LDS transpose epilogue.
__global__ __launch_bounds__(128, 3) void gemm_qkv(
    const f16* __restrict__ q16, const f16* __restrict__ k16,
    const f16* __restrict__ v16, const f16* __restrict__ wq,
    const f16* __restrict__ wk, const f16* __restrict__ wv,
    const float* __restrict__ bq, const float* __restrict__ bk,
    const float* __restrict__ bv, const int* __restrict__ mask,
    f16* __restrict__ qhp, f16* __restrict__ khp, f16* __restrict__ vhT,
    float scale) {
  __shared__ __align__(16) char SMEM[24576];
  f16* Alds = (f16*)SMEM;              // 64x64 f16 = 8 KB
  f16* Blds = (f16*)(SMEM + 8192);     // 128x64 f16 = 16 KB

  const int raw = blockIdx.x;
  const int bid = (raw & 7) * 192 + (raw >> 3);
  const int prob = bid / 512;
  const int sub = bid - prob * 512;
  const int mt = sub >> 2, nt = sub & 3;  // mt 0..127 (64 rows), nt 0..3 (128 cols)

  const f16* A = prob == 0 ? q16 : (prob == 1 ? k16 : v16);
  const f16* W = prob == 0 ? wq : (prob == 1 ? wk : wv);
  const float* bias = prob == 0 ? bq : (prob == 1 ? bk : bv);

  const int tid = threadIdx.x;
  const int w = tid >> 6, lane = tid & 63;
  const int l15 = lane & 15, lg = lane >> 4;

  f32x4 acc[2][8];
#pragma unroll
  for (int mi = 0; mi < 2; ++mi)
#pragma unroll
    for (int nj = 0; nj < 8; ++nj) acc[mi][nj] = {};

  for (int kt = 0; kt < 8; ++kt) {
#pragma unroll
    for (int i = 0; i < 4; ++i) {
      int g = i * 128 + tid;
      int row = g >> 3, jj = g & 7;
      int kb = kt * 128 + ((jj ^ (row & 7)) << 4);
      gload_lds16((const char*)A + (size_t)(mt * 64 + row) * 1024 + kb,
                  (char*)Alds + g * 16);
    }
#pragma unroll
    for (int i = 0; i < 8; ++i) {
      int g = i * 128 + tid;
      int row = g >> 3, jj = g & 7;
      int kb = kt * 128 + ((jj ^ (row & 7)) << 4);
      gload_lds16((const char*)W + (size_t)(nt * 128 + row) * 1024 + kb,
                  (char*)Blds + g * 16);
    }
    __syncthreads();

#pragma unroll
    for (int h2 = 0; h2 < 2; ++h2) {
      f16x8 af[2], bf[8];
#pragma unroll
      for (int mi = 0; mi < 2; ++mi) {
        int row = w * 32 + mi * 16 + l15;
        int bo = (h2 * 64 + (lg << 4)) ^ ((row & 7) << 4);
        af[mi] = *(const f16x8*)((const char*)Alds + row * 128 + bo);
      }
#pragma unroll
      for (int nj = 0; nj < 8; ++nj) {
        int row = nj * 16 + l15;
        int bo = (h2 * 64 + (lg << 4)) ^ ((row & 7) << 4);
        bf[nj] = *(const f16x8*)((const char*)Blds + row * 128 + bo);
      }
#pragma unroll
      for (int mi = 0; mi < 2; ++mi)
#pragma unroll
        for (int nj = 0; nj < 8; ++nj)
          acc[mi][nj] = __builtin_amdgcn_mfma_f32_16x16x32_f16(
              af[mi], bf[nj], acc[mi][nj], 0, 0, 0);
    }
    __syncthreads();
  }

  const int base_m = mt * 64 + w * 32;
  const int base_n = nt * 128;
  float bb[8];
#pragma unroll
  for (int nj = 0; nj < 8; ++nj) bb[nj] = bias[base_n + nj * 16 + l15];

  if (prob != 2) {
    f16* outp = (prob == 0) ? qhp : khp;
#pragma unroll
    for (int mi = 0; mi < 2; ++mi) {
#pragma unroll
      for (int r = 0; r < 4; ++r) {
        int m = base_m + mi * 16 + (lg << 2) + r;
        int b = m >> 11, t = m & (TT - 1);
        float sc = (prob == 0) ? scale : (mask[(b << 11) + t] ? 1.f : 0.f);
#pragma unroll
        for (int nj = 0; nj < 8; ++nj) {
          int n = base_n + nj * 16 + l15;
          int h = n >> 6, c = n & 63;
          float val = (acc[mi][nj][r] + bb[nj]) * sc;
          outp[(((size_t)(b * HH + h) * TT + t) << 6) + c] = (f16)val;
        }
      }
    }
  } else {
    // ---- LDS-transpose epilogue: acc (t x n) -> vhT (B,H,64,T) ----
    // T[n][t_local] f16, stride 72 to spread banks. 128*72*2 = 18432 B.
    __syncthreads();  // Alds/Blds dead
    f16* T = (f16*)SMEM;
    const int b = base_m >> 11;           // block fully inside one batch
    const int t_base = base_m & (TT - 1);  // includes w*32
#pragma unroll
    for (int mi = 0; mi < 2; ++mi) {
      float sc_r[4];
#pragma unroll
      for (int r = 0; r < 4; ++r) {
        int t = (t_base + mi * 16 + (lg << 2) + r) & (TT - 1);
        sc_r[r] = mask[(b << 11) + t] ? 1.f : 0.f;
      }
#pragma unroll
      for (int nj = 0; nj < 8; ++nj) {
        f16x4 pk;
#pragma unroll
        for (int r = 0; r < 4; ++r)
          pk[r] = (f16)((acc[mi][nj][r] + bb[nj]) * sc_r[r]);
        // t_local within the 64-row block = w*32 + mi*16 + lg*4
        *(f16x4*)(&T[(nj * 16 + l15) * 72 + w * 32 + mi * 16 + (lg << 2)]) = pk;
      }
    }
    __syncthreads();
    // write out: n = tid>>3 + i*16 (0..127), chunk = tid&7 -> 16B along t
    const int tb = (mt & 31) * 64;  // t offset within batch
#pragma unroll
    for (int i = 0; i < 8; ++i) {
      int n = (tid >> 3) + i * 16;
      int head = (base_n + n) >> 6, c = (base_n + n) & 63;
      f16x8 val = *(const f16x8*)(&T[n * 72 + (tid & 7) * 8]);
      *(f16x8*)(vhT + ((size_t)(b * HH + head) * 64 + c) * TT + tb +
                (tid & 7) * 8) = val;
    }
  }
}

// ---------------- flash attention, 32x32 MFMA, k-split, KBLK=32 ------------
__global__ __launch_bounds__(256, 4) void attn_k(
    const f16* __restrict__ qh, const f16* __restrict__ kh,
    const f16* __restrict__ vhT, const float* __restrict__ cnt,
    f16* __restrict__ att) {
  __shared__ __align__(16) char SMEM[33792];

  const int bid = blockIdx.x;
  const int xcd = bid & 7, jj_ = bid >> 3;
  const int bh = xcd * 4 + (jj_ >> 5);  // 4 bh per XCD -> 2MB L2 working set
  const int qt = jj_ & 31;
  const int b = bh >> 3, hd = bh & 7;
  const char* Kp = (const char*)(kh + (size_t)bh * (TT * 64));
  const char* Vp = (const char*)(vhT + (size_t)bh * (64 * TT));
  const f16* Q = qh + (size_t)bh * (TT * 64);

  const int tid = threadIdx.x;
  const int w = tid >> 6, lane = tid & 63;
  const int l31 = lane & 31, hi = lane >> 5;
  const int qg = w & 1, hf = w >> 1;
  const int ht = tid & 127;

  const int qrow = qt * 64 + qg * 32 + l31;
  f16x8 qf[4];
#pragma unroll
  for (int c = 0; c < 4; ++c)
    qf[c] = *(const f16x8*)(Q + (size_t)qrow * 64 + c * 16 + hi * 8);

  f32x16 o0 = {}, o1 = {};
  float lsum = 0.f;

#define STAGE(tile, bufp)                                                     \
  {                                                                           \
    const char* Kg = Kp + (size_t)(tile)*4096;                                \
    const char* Vg = Vp + (size_t)(tile)*64;                                  \
    char* Kl = SMEM + (hf * 2 + (bufp)) * 4096;                               \
    char* Vl = SMEM + 16384 + (hf * 2 + (bufp)) * 4096;                       \
    _Pragma("unroll") for (int i2 = 0; i2 < 2; ++i2) {                        \
      int gK = i2 * 128 + ht;                                                 \
      int rK = gK >> 3, jK = gK & 7;                                          \
      gload_lds16(Kg + rK * 128 + ((jK ^ (rK & 7)) << 4), Kl + gK * 16);      \
      int gV = i2 * 128 + ht;                                                 \
      int rV = gV >> 2, jV = gV & 3;                                          \
      gload_lds16(Vg + (size_t)rV * 4096 + ((jV ^ ((rV >> 1) & 3)) << 4),     \
                  Vl + gV * 16);                                              \
    }                                                                         \
  }

  STAGE(hf * 32, 0);
  __syncthreads();

  for (int it = 0; it < 32; ++it) {
    const int cur = it & 1;
    if (it < 31) STAGE(hf * 32 + it + 1, cur ^ 1);

    const char* Kl = SMEM + (hf * 2 + cur) * 4096;
    const char* Vl = SMEM + 16384 + (hf * 2 + cur) * 4096;

    f32x16 s0 = {};
    __builtin_amdgcn_s_setprio(1);
#pragma unroll
    for (int s = 0; s < 4; ++s) {
      f16x8 af = *(const f16x8*)(Kl + l31 * 128 + (((2 * s + hi) ^ (l31 & 7)) << 4));
      s0 = __builtin_amdgcn_mfma_f32_32x32x16_f16(af, qf[s], s0, 0, 0, 0);
    }
    __builtin_amdgcn_s_setprio(0);

    float ls = 0.f;
#pragma unroll
    for (int r = 0; r < 16; ++r) {
      s0[r] = exp2f(s0[r]);
      ls += s0[r];
    }
    lsum += ls;

    f16x8 pa0 = mkpa(s0[0], s0[1], s0[2], s0[3], s0[4], s0[5], s0[6], s0[7]);
    f16x8 pa1 = mkpa(s0[8], s0[9], s0[10], s0[11], s0[12], s0[13], s0[14], s0[15]);

    __builtin_amdgcn_s_setprio(1);
    {
      int c0 = l31, sw0 = (c0 >> 1) & 3;
      f16x8 vf00 = *(const f16x8*)(Vl + c0 * 64 + (((0 + hi) ^ sw0) << 4));
      f16x8 vf01 = *(const f16x8*)(Vl + c0 * 64 + (((2 + hi) ^ sw0) << 4));
      o0 = __builtin_amdgcn_mfma_f32_32x32x16_f16(pa0, vf00, o0, 0, 0, 0);
      o0 = __builtin_amdgcn_mfma_f32_32x32x16_f16(pa1, vf01, o0, 0, 0, 0);
      int c1 = 32 + l31, sw1 = (c1 >> 1) & 3;
      f16x8 vf10 = *(const f16x8*)(Vl + c1 * 64 + (((0 + hi) ^ sw1) << 4));
      f16x8 vf11 = *(const f16x8*)(Vl + c1 * 64 + (((2 + hi) ^ sw1) << 4));
      o1 = __builtin_amdgcn_mfma_f32_32x32x16_f16(pa0, vf10, o1, 0, 0, 0);
      o1 = __builtin_amdgcn_mfma_f32_32x32x16_f16(pa1, vf11, o1, 0, 0, 0);
    }
    __builtin_amdgcn_s_setprio(0);
    __syncthreads();
  }
#undef STAGE

  float* R = (float*)SMEM;
  float* L = (float*)(SMEM + 32768);
  const int rbase = qg * 2176;
  if (hf == 1) {
#pragma unroll
    for (int rb = 0; rb < 4; ++rb) {
      f32x4 t0 = {o0[4 * rb], o0[4 * rb + 1], o0[4 * rb + 2], o0[4 * rb + 3]};
      *(f32x4*)(R + rbase + rb * 256 + lane * 4) = t0;
      f32x4 t1 = {o1[4 * rb], o1[4 * rb + 1], o1[4 * rb + 2], o1[4 * rb + 3]};
      *(f32x4*)(R + rbase + 1024 + rb * 256 + lane * 4) = t1;
    }
    R[rbase + 2048 + lane] = lsum;
  }
  __syncthreads();
  if (hf == 0) {
#pragma unroll
    for (int rb = 0; rb < 4; ++rb) {
      f32x4 t0 = *(const f32x4*)(R + rbase + rb * 256 + lane * 4);
      f32x4 t1 = *(const f32x4*)(R + rbase + 1024 + rb * 256 + lane * 4);
#pragma unroll
      for (int q = 0; q < 4; ++q) {
        o0[4 * rb + q] += t0[q];
        o1[4 * rb + q] += t1[q];
      }
    }
    lsum += R[rbase + 2048 + lane];
    float lq = lsum + __shfl_xor(lsum, 32);
    lq -= cnt[b];
    L[qg * 32 + l31] = lq;

#pragma unroll
    for (int r = 0; r < 16; ++r) {
      int qloc = (r & 3) + 8 * (r >> 2) + 4 * hi;
      float inv = 1.0f / L[qg * 32 + qloc];
      int qgrow = qt * 64 + qg * 32 + qloc;
      size_t ob = ((size_t)(b * TT + qgrow) << 9) + hd * 64;
      att[ob + l31] = (f16)(o0[r] * inv);
      att[ob + 32 + l31] = (f16)(o1[r] * inv);
    }
  }
}

// ---------------- output projection: out = att @ Wo^T + bo (f32) ----------
__global__ __launch_bounds__(256) void gemm_out(const f16* __restrict__ A,
                                                const f16* __restrict__ W,
                                                const float* __restrict__ bias,
                                                float* __restrict__ out) {
  __shared__ __align__(16) f16 Alds[64 * 64];
  __shared__ __align__(16) f16 Blds[128 * 64];

  const int nt = blockIdx.x & 3;
  const int mt = blockIdx.x >> 2;  // 0..127
  const int tid = threadIdx.x;
  const int w = tid >> 6, lane = tid & 63;
  const int l15 = lane & 15, lg = lane >> 4;
  const int wm = w >> 1, wn = w & 1;

  f32x4 acc[2][4];
#pragma unroll
  for (int mi = 0; mi < 2; ++mi)
#pragma unroll
    for (int nj = 0; nj < 4; ++nj) acc[mi][nj] = {};

  for (int kt = 0; kt < 8; ++kt) {
#pragma unroll
    for (int i = 0; i < 2; ++i) {
      int g = (i * 4 + w) * 64 + lane;  // 0..511
      int row = g >> 3, jj = g & 7;
      int kb = kt * 128 + ((jj ^ (row & 7)) << 4);
      gload_lds16((const char*)A + (size_t)(mt * 64 + row) * 1024 + kb,
                  (char*)Alds + g * 16);
    }
#pragma unroll
    for (int i = 0; i < 4; ++i) {
      int g = (i * 4 + w) * 64 + lane;  // 0..1023
      int row = g >> 3, jj = g & 7;
      int kb = kt * 128 + ((jj ^ (row & 7)) << 4);
      gload_lds16((const char*)W + (size_t)(nt * 128 + row) * 1024 + kb,
                  (char*)Blds + g * 16);
    }
    __syncthreads();

#pragma unroll
    for (int h2 = 0; h2 < 2; ++h2) {
      f16x8 af[2], bf[4];
#pragma unroll
      for (int mi = 0; mi < 2; ++mi) {
        int row = wm * 32 + mi * 16 + l15;
        int bo = (h2 * 64 + (lg << 4)) ^ ((row & 7) << 4);
        af[mi] = *(const f16x8*)((const char*)Alds + row * 128 + bo);
      }
#pragma unroll
      for (int nj = 0; nj < 4; ++nj) {
        int row = wn * 64 + nj * 16 + l15;
        int bo = (h2 * 64 + (lg << 4)) ^ ((row & 7) << 4);
        bf[nj] = *(const f16x8*)((const char*)Blds + row * 128 + bo);
      }
#pragma unroll
      for (int mi = 0; mi < 2; ++mi)
#pragma unroll
        for (int nj = 0; nj < 4; ++nj)
          acc[mi][nj] = __builtin_amdgcn_mfma_f32_16x16x32_f16(
              af[mi], bf[nj], acc[mi][nj], 0, 0, 0);
    }
    __syncthreads();
  }

  const int base_m = mt * 64 + wm * 32;
  const int base_n = nt * 128 + wn * 64;
#pragma unroll
  for (int mi = 0; mi < 2; ++mi)
#pragma unroll
    for (int nj = 0; nj < 4; ++nj) {
      int n = base_n + nj * 16 + l15;
      float bv = bias[n];
#pragma unroll
      for (int r = 0; r < 4; ++r) {
        int m = base_m + mi * 16 + (lg << 2) + r;
        out[(size_t)m * 512 + n] = acc[mi][nj][r] + bv;
      }
    }
}

// ---------------- host launch ----------------
extern "C" void kernel_launch(void* const* d_in, const int* in_sizes, int n_in,
                              void* d_out, int out_size, void* d_ws, size_t ws_size,
                              hipStream_t stream) {
  (void)in_sizes; (void)n_in; (void)out_size; (void)ws_size;
  const float* q = (const float*)d_in[0];
  const float* k = (const float*)d_in[1];
  const float* v = (const float*)d_in[2];
  const int* mask = (const int*)d_in[3];
  const float* Wq = (const float*)d_in[4];
  const float* bq = (const float*)d_in[5];
  const float* Wk = (const float*)d_in[6];
  const float* bk = (const float*)d_in[7];
  const float* Wv = (const float*)d_in[8];
  const float* bv = (const float*)d_in[9];
  const float* Wo = (const float*)d_in[10];
  const float* bo = (const float*)d_in[11];

  char* ws = (char*)d_ws;
  const size_t SZ = (size_t)8192 * 512 * 2;  // 8 MiB per (B,T,D) f16 tensor
  f16* q16 = (f16*)(ws + 0 * SZ);  // q16,k16,v16 contiguous for prep cvt
  f16* k16 = (f16*)(ws + 1 * SZ);
  f16* v16 = (f16*)(ws + 2 * SZ);
  f16* qhp = (f16*)(ws + 3 * SZ);
  f16* khp = (f16*)(ws + 4 * SZ);
  f16* vhT = (f16*)(ws + 5 * SZ);
  f16* w16 = (f16*)(ws + 6 * SZ);  // 4 x 512x512 f16, contiguous
  f16* wq16 = w16;
  f16* wk16 = w16 + 262144;
  f16* wv16 = w16 + 2 * 262144;
  f16* wo16 = w16 + 3 * 262144;
  float* cntb = (float*)(ws + 6 * SZ + 4 * 262144 * sizeof(f16));
  f16* att = (f16*)(ws + 0 * SZ);  // alias q16 (dead after gemm_qkv)

  prep<<<13316, 256, 0, stream>>>(q, k, v, Wq, Wk, Wv, Wo, mask, q16, w16, cntb);

  // 512^-0.5 * log2(e): fold softmax scale + exp2 conversion into qh
  const float scale = 0.044194173824159216f * 1.4426950408889634f;
  gemm_qkv<<<1536, 128, 0, stream>>>(q16, k16, v16, wq16, wk16, wv16, bq, bk, bv,
                                     mask, qhp, khp, vhT, scale);

  attn_k<<<1024, 256, 0, stream>>>(qhp, khp, vhT, cntb, att);

  gemm_out<<<512, 256, 0, stream>>>(att, wo16, bo, (float*)d_out);
}

// Round 9
// 194.514 us; speedup vs baseline: 1.4928x; 1.0510x over previous
//
#include <hip/hip_runtime.h>
#include <stdint.h>

typedef _Float16 f16;
typedef __attribute__((ext_vector_type(4))) _Float16 f16x4;
typedef __attribute__((ext_vector_type(8))) _Float16 f16x8;
typedef __attribute__((ext_vector_type(4))) float f32x4;
typedef __attribute__((ext_vector_type(16))) float f32x16;
typedef __attribute__((ext_vector_type(4))) int int4v;

#define TT 2048
#define HH 8

static __device__ __forceinline__ void gload_lds16(const void* g, void* l) {
  __builtin_amdgcn_global_load_lds((const __attribute__((address_space(1))) void*)g,
                                   (__attribute__((address_space(3))) void*)l, 16, 0, 0);
}

static __device__ __forceinline__ int pkf16(float a, float b) {
  auto h = __builtin_amdgcn_cvt_pkrtz(a, b);  // __fp16 ext_vector(2)
  return __builtin_bit_cast(int, h);
}

static __device__ __forceinline__ void plswap(int& a, int& b) {
  asm("v_permlane32_swap_b32 %0, %1" : "+v"(a), "+v"(b));
}

// Build PV A-fragment (rows=q=lane&31, k-slots=(lane>>5)*8+j) from swapped-QK
// D regs p0..p7 (k = (r&3)+8*(r>>2)+4*hi within a 16-k block).
static __device__ __forceinline__ f16x8 mkpa(float p0, float p1, float p2, float p3,
                                             float p4, float p5, float p6, float p7) {
  int a0 = pkf16(p0, p1), a1 = pkf16(p2, p3);
  int b0 = pkf16(p4, p5), b1 = pkf16(p6, p7);
  plswap(a0, b0);
  plswap(a1, b1);
  int4v w = {a0, a1, b0, b1};
  return __builtin_bit_cast(f16x8, w);
}

// ---------------- merged prep: cvt q/k/v, cvt weights, mask count ----------
__global__ __launch_bounds__(256) void prep(
    const float* __restrict__ q, const float* __restrict__ k,
    const float* __restrict__ v, const float* __restrict__ Wq,
    const float* __restrict__ Wk, const float* __restrict__ Wv,
    const float* __restrict__ Wo, const int* __restrict__ mask,
    f16* __restrict__ qkv16, f16* __restrict__ w16, float* __restrict__ cnt) {
  const int bid = blockIdx.x;
  if (bid < 12288) {
    int g = bid * 256 + threadIdx.x;
    int sel = g >> 20, off = g & 1048575;
    const float* s = sel == 0 ? q : sel == 1 ? k : v;
    float4 val = ((const float4*)s)[off];
    f16x4 o = {(_Float16)val.x, (_Float16)val.y, (_Float16)val.z, (_Float16)val.w};
    ((f16x4*)qkv16)[g] = o;
  } else if (bid < 13312) {
    int g = (bid - 12288) * 256 + threadIdx.x;
    int sel = g >> 16, off = g & 65535;
    const float* s = sel == 0 ? Wq : sel == 1 ? Wk : (sel == 2 ? Wv : Wo);
    float4 val = ((const float4*)s)[off];
    f16x4 o = {(_Float16)val.x, (_Float16)val.y, (_Float16)val.z, (_Float16)val.w};
    ((f16x4*)w16)[g] = o;
  } else {
    __shared__ int red[256];
    int b = bid - 13312, t = threadIdx.x;
    int s = 0;
#pragma unroll
    for (int i = 0; i < 8; ++i) s += (mask[b * 2048 + t * 8 + i] == 0) ? 1 : 0;
    red[t] = s;
    __syncthreads();
    for (int off = 128; off > 0; off >>= 1) {
      if (t < off) red[t] += red[t + off];
      __syncthreads();
    }
    if (t == 0) cnt[b] = (float)red[0];
  }
}

// ---------------- merged q/k/v projection GEMM, 64x128 tiles --------------
__global__ __launch_bounds__(128, 3) void gemm_qkv(
    const f16* __restrict__ q16, const f16* __restrict__ k16,
    const f16* __restrict__ v16, const f16* __restrict__ wq,
    const f16* __restrict__ wk, const f16* __restrict__ wv,
    const float* __restrict__ bq, const float* __restrict__ bk,
    const float* __restrict__ bv, const int* __restrict__ mask,
    f16* __restrict__ qhp, f16* __restrict__ khp, f16* __restrict__ vhT,
    float scale) {
  __shared__ __align__(16) char SMEM[24576];
  f16* Alds = (f16*)SMEM;              // 64x64 f16 = 8 KB
  f16* Blds = (f16*)(SMEM + 8192);     // 128x64 f16 = 16 KB

  const int raw = blockIdx.x;
  const int bid = (raw & 7) * 192 + (raw >> 3);
  const int prob = bid / 512;
  const int sub = bid - prob * 512;
  const int mt = sub >> 2, nt = sub & 3;

  const f16* A = prob == 0 ? q16 : (prob == 1 ? k16 : v16);
  const f16* W = prob == 0 ? wq : (prob == 1 ? wk : wv);
  const float* bias = prob == 0 ? bq : (prob == 1 ? bk : bv);

  const int tid = threadIdx.x;
  const int w = tid >> 6, lane = tid & 63;
  const int l15 = lane & 15, lg = lane >> 4;

  f32x4 acc[2][8];
#pragma unroll
  for (int mi = 0; mi < 2; ++mi)
#pragma unroll
    for (int nj = 0; nj < 8; ++nj) acc[mi][nj] = {};

  for (int kt = 0; kt < 8; ++kt) {
#pragma unroll
    for (int i = 0; i < 4; ++i) {
      int g = i * 128 + tid;
      int row = g >> 3, jj = g & 7;
      int kb = kt * 128 + ((jj ^ (row & 7)) << 4);
      gload_lds16((const char*)A + (size_t)(mt * 64 + row) * 1024 + kb,
                  (char*)Alds + g * 16);
    }
#pragma unroll
    for (int i = 0; i < 8; ++i) {
      int g = i * 128 + tid;
      int row = g >> 3, jj = g & 7;
      int kb = kt * 128 + ((jj ^ (row & 7)) << 4);
      gload_lds16((const char*)W + (size_t)(nt * 128 + row) * 1024 + kb,
                  (char*)Blds + g * 16);
    }
    __syncthreads();

#pragma unroll
    for (int h2 = 0; h2 < 2; ++h2) {
      f16x8 af[2], bf[8];
#pragma unroll
      for (int mi = 0; mi < 2; ++mi) {
        int row = w * 32 + mi * 16 + l15;
        int bo = (h2 * 64 + (lg << 4)) ^ ((row & 7) << 4);
        af[mi] = *(const f16x8*)((const char*)Alds + row * 128 + bo);
      }
#pragma unroll
      for (int nj = 0; nj < 8; ++nj) {
        int row = nj * 16 + l15;
        int bo = (h2 * 64 + (lg << 4)) ^ ((row & 7) << 4);
        bf[nj] = *(const f16x8*)((const char*)Blds + row * 128 + bo);
      }
#pragma unroll
      for (int mi = 0; mi < 2; ++mi)
#pragma unroll
        for (int nj = 0; nj < 8; ++nj)
          acc[mi][nj] = __builtin_amdgcn_mfma_f32_16x16x32_f16(
              af[mi], bf[nj], acc[mi][nj], 0, 0, 0);
    }
    __syncthreads();
  }

  const int base_m = mt * 64 + w * 32;
  const int base_n = nt * 128;
  float bb[8];
#pragma unroll
  for (int nj = 0; nj < 8; ++nj) bb[nj] = bias[base_n + nj * 16 + l15];

  if (prob != 2) {
    f16* outp = (prob == 0) ? qhp : khp;
#pragma unroll
    for (int mi = 0; mi < 2; ++mi) {
#pragma unroll
      for (int r = 0; r < 4; ++r) {
        int m = base_m + mi * 16 + (lg << 2) + r;
        int b = m >> 11, t = m & (TT - 1);
        float sc = (prob == 0) ? scale : (mask[(b << 11) + t] ? 1.f : 0.f);
#pragma unroll
        for (int nj = 0; nj < 8; ++nj) {
          int n = base_n + nj * 16 + l15;
          int h = n >> 6, c = n & 63;
          float val = (acc[mi][nj][r] + bb[nj]) * sc;
          outp[(((size_t)(b * HH + h) * TT + t) << 6) + c] = (f16)val;
        }
      }
    }
  } else {
    // ---- LDS-transpose epilogue: acc (t x n) -> vhT (B,H,64,T) ----
    __syncthreads();
    f16* T = (f16*)SMEM;
    const int b = base_m >> 11;
    const int t_base = base_m & (TT - 1);
#pragma unroll
    for (int mi = 0; mi < 2; ++mi) {
      float sc_r[4];
#pragma unroll
      for (int r = 0; r < 4; ++r) {
        int t = (t_base + mi * 16 + (lg << 2) + r) & (TT - 1);
        sc_r[r] = mask[(b << 11) + t] ? 1.f : 0.f;
      }
#pragma unroll
      for (int nj = 0; nj < 8; ++nj) {
        f16x4 pk;
#pragma unroll
        for (int r = 0; r < 4; ++r)
          pk[r] = (f16)((acc[mi][nj][r] + bb[nj]) * sc_r[r]);
        *(f16x4*)(&T[(nj * 16 + l15) * 72 + w * 32 + mi * 16 + (lg << 2)]) = pk;
      }
    }
    __syncthreads();
    const int tb = (mt & 31) * 64;
#pragma unroll
    for (int i = 0; i < 8; ++i) {
      int n = (tid >> 3) + i * 16;
      int head = (base_n + n) >> 6, c = (base_n + n) & 63;
      f16x8 val = *(const f16x8*)(&T[n * 72 + (tid & 7) * 8]);
      *(f16x8*)(vhT + ((size_t)(b * HH + head) * 64 + c) * TT + tb +
                (tid & 7) * 8) = val;
    }
  }
}

// ---------------- flash attention, 32x32 MFMA, k-split, KBLK=32 ------------
// VALU-lean: lsum via MFMA (ones-column), strength-reduced staging,
// unroll-by-2 hardcoded double buffers. exp via library exp2f (the raw
// inline-asm v_exp_f32 caused a TRANS-hazard miscompute in R8).
__global__ __launch_bounds__(256, 4) void attn_k(
    const f16* __restrict__ qh, const f16* __restrict__ kh,
    const f16* __restrict__ vhT, const float* __restrict__ cnt,
    f16* __restrict__ att) {
  __shared__ __align__(16) char SMEM[32768];

  const int bid = blockIdx.x;
  const int xcd = bid & 7, jj_ = bid >> 3;
  const int bh = xcd * 4 + (jj_ >> 5);  // 4 bh per XCD
  const int qt = jj_ & 31;
  const int b = bh >> 3, hd = bh & 7;
  const char* Kp = (const char*)(kh + (size_t)bh * (TT * 64));
  const char* Vp = (const char*)(vhT + (size_t)bh * (64 * TT));
  const f16* Q = qh + (size_t)bh * (TT * 64);

  const int tid = threadIdx.x;
  const int w = tid >> 6, lane = tid & 63;
  const int l31 = lane & 31, hi = lane >> 5;
  const int qg = w & 1, hf = w >> 1;
  const int ht = tid & 127;

  const int qrow = qt * 64 + qg * 32 + l31;
  f16x8 qf[4];
#pragma unroll
  for (int c = 0; c < 4; ++c)
    qf[c] = *(const f16x8*)(Q + (size_t)qrow * 64 + c * 16 + hi * 8);

  const f16x8 onesf = {(_Float16)1, (_Float16)1, (_Float16)1, (_Float16)1,
                       (_Float16)1, (_Float16)1, (_Float16)1, (_Float16)1};

  // ---- loop-invariant staging offsets ----
  const int g0 = ht, g1 = 128 + ht;
  const int rK0 = g0 >> 3, jK0 = g0 & 7, rK1 = g1 >> 3, jK1 = g1 & 7;
  const int rV0 = g0 >> 2, jV0 = g0 & 3, rV1 = g1 >> 2, jV1 = g1 & 3;
  const char* kp0 = Kp + (size_t)(hf * 32) * 4096 + rK0 * 128 + ((jK0 ^ (rK0 & 7)) << 4);
  const char* kp1 = Kp + (size_t)(hf * 32) * 4096 + rK1 * 128 + ((jK1 ^ (rK1 & 7)) << 4);
  const char* vp0 = Vp + (size_t)(hf * 32) * 64 + (size_t)rV0 * 4096 + ((jV0 ^ ((rV0 >> 1) & 3)) << 4);
  const char* vp1 = Vp + (size_t)(hf * 32) * 64 + (size_t)rV1 * 4096 + ((jV1 ^ ((rV1 >> 1) & 3)) << 4);

  // LDS dests (linear in lane)
  char* dk0a = SMEM + (hf * 2 + 0) * 4096 + g0 * 16;
  char* dk0b = SMEM + (hf * 2 + 0) * 4096 + g1 * 16;
  char* dk1a = SMEM + (hf * 2 + 1) * 4096 + g0 * 16;
  char* dk1b = SMEM + (hf * 2 + 1) * 4096 + g1 * 16;
  char* dv0a = SMEM + 16384 + (hf * 2 + 0) * 4096 + g0 * 16;
  char* dv0b = SMEM + 16384 + (hf * 2 + 0) * 4096 + g1 * 16;
  char* dv1a = SMEM + 16384 + (hf * 2 + 1) * 4096 + g0 * 16;
  char* dv1b = SMEM + 16384 + (hf * 2 + 1) * 4096 + g1 * 16;

  // LDS read addresses (precomputed, indexed by literal after unroll)
  const char* kr[2][4];
  const char* vr[2][4];
  {
    const char* KlB[2] = {SMEM + (hf * 2 + 0) * 4096, SMEM + (hf * 2 + 1) * 4096};
    const char* VlB[2] = {SMEM + 16384 + (hf * 2 + 0) * 4096,
                          SMEM + 16384 + (hf * 2 + 1) * 4096};
    const int sw0 = (l31 >> 1) & 3;
#pragma unroll
    for (int bu = 0; bu < 2; ++bu) {
#pragma unroll
      for (int s = 0; s < 4; ++s)
        kr[bu][s] = KlB[bu] + l31 * 128 + (((2 * s + hi) ^ (l31 & 7)) << 4);
      vr[bu][0] = VlB[bu] + l31 * 64 + (((0 + hi) ^ sw0) << 4);
      vr[bu][1] = VlB[bu] + l31 * 64 + (((2 + hi) ^ sw0) << 4);
      vr[bu][2] = VlB[bu] + (32 + l31) * 64 + (((0 + hi) ^ sw0) << 4);
      vr[bu][3] = VlB[bu] + (32 + l31) * 64 + (((2 + hi) ^ sw0) << 4);
    }
  }

  f32x16 o0 = {}, o1 = {}, lD = {};

#define PREF0()                                                \
  {                                                            \
    gload_lds16(kp0, dk0a); gload_lds16(kp1, dk0b);            \
    gload_lds16(vp0, dv0a); gload_lds16(vp1, dv0b);            \
    kp0 += 4096; kp1 += 4096; vp0 += 64; vp1 += 64;            \
  }
#define PREF1()                                                \
  {                                                            \
    gload_lds16(kp0, dk1a); gload_lds16(kp1, dk1b);            \
    gload_lds16(vp0, dv1a); gload_lds16(vp1, dv1b);            \
    kp0 += 4096; kp1 += 4096; vp0 += 64; vp1 += 64;            \
  }
#define COMPUTE(BUF)                                                          \
  {                                                                           \
    f32x16 s0 = {};                                                           \
    __builtin_amdgcn_s_setprio(1);                                            \
    s0 = __builtin_amdgcn_mfma_f32_32x32x16_f16(                              \
        *(const f16x8*)kr[BUF][0], qf[0], s0, 0, 0, 0);                       \
    s0 = __builtin_amdgcn_mfma_f32_32x32x16_f16(                              \
        *(const f16x8*)kr[BUF][1], qf[1], s0, 0, 0, 0);                       \
    s0 = __builtin_amdgcn_mfma_f32_32x32x16_f16(                              \
        *(const f16x8*)kr[BUF][2], qf[2], s0, 0, 0, 0);                       \
    s0 = __builtin_amdgcn_mfma_f32_32x32x16_f16(                              \
        *(const f16x8*)kr[BUF][3], qf[3], s0, 0, 0, 0);                       \
    __builtin_amdgcn_s_setprio(0);                                            \
    _Pragma("unroll") for (int r = 0; r < 16; ++r) s0[r] = exp2f(s0[r]);      \
    f16x8 pa0 = mkpa(s0[0], s0[1], s0[2], s0[3], s0[4], s0[5], s0[6], s0[7]); \
    f16x8 pa1 =                                                               \
        mkpa(s0[8], s0[9], s0[10], s0[11], s0[12], s0[13], s0[14], s0[15]);   \
    __builtin_amdgcn_s_setprio(1);                                            \
    lD = __builtin_amdgcn_mfma_f32_32x32x16_f16(pa0, onesf, lD, 0, 0, 0);     \
    lD = __builtin_amdgcn_mfma_f32_32x32x16_f16(pa1, onesf, lD, 0, 0, 0);     \
    o0 = __builtin_amdgcn_mfma_f32_32x32x16_f16(                              \
        pa0, *(const f16x8*)vr[BUF][0], o0, 0, 0, 0);                         \
    o0 = __builtin_amdgcn_mfma_f32_32x32x16_f16(                              \
        pa1, *(const f16x8*)vr[BUF][1], o0, 0, 0, 0);                         \
    o1 = __builtin_amdgcn_mfma_f32_32x32x16_f16(                              \
        pa0, *(const f16x8*)vr[BUF][2], o1, 0, 0, 0);                         \
    o1 = __builtin_amdgcn_mfma_f32_32x32x16_f16(                              \
        pa1, *(const f16x8*)vr[BUF][3], o1, 0, 0, 0);                         \
    __builtin_amdgcn_s_setprio(0);                                            \
  }

  PREF0();  // tile base -> buf0
  __syncthreads();

  for (int i2 = 0; i2 < 16; ++i2) {
    PREF1();      // tile 2*i2+1 -> buf1
    COMPUTE(0);   // tile 2*i2
    __syncthreads();
    if (i2 < 15) PREF0();  // tile 2*i2+2 -> buf0
    COMPUTE(1);   // tile 2*i2+1
    __syncthreads();
  }
#undef PREF0
#undef PREF1
#undef COMPUTE

  // ---- cross-half reduction (K/V buffers dead) ----
  float* R = (float*)SMEM;
  const int rbase = qg * 2176;
  if (hf == 1) {
#pragma unroll
    for (int rb = 0; rb < 4; ++rb) {
      f32x4 t0 = {o0[4 * rb], o0[4 * rb + 1], o0[4 * rb + 2], o0[4 * rb + 3]};
      *(f32x4*)(R + rbase + rb * 256 + lane * 4) = t0;
      f32x4 t1 = {o1[4 * rb], o1[4 * rb + 1], o1[4 * rb + 2], o1[4 * rb + 3]};
      *(f32x4*)(R + rbase + 1024 + rb * 256 + lane * 4) = t1;
    }
    if (l31 == 0) {
#pragma unroll
      for (int r = 0; r < 16; ++r)
        R[rbase + 2048 + ((r & 3) + 8 * (r >> 2) + 4 * hi)] = lD[r];
    }
  }
  __syncthreads();
  if (hf == 0) {
#pragma unroll
    for (int rb = 0; rb < 4; ++rb) {
      f32x4 t0 = *(const f32x4*)(R + rbase + rb * 256 + lane * 4);
      f32x4 t1 = *(const f32x4*)(R + rbase + 1024 + rb * 256 + lane * 4);
#pragma unroll
      for (int q = 0; q < 4; ++q) {
        o0[4 * rb + q] += t0[q];
        o1[4 * rb + q] += t1[q];
      }
    }
    const float cb = cnt[b];
#pragma unroll
    for (int r = 0; r < 16; ++r) {
      int qloc = (r & 3) + 8 * (r >> 2) + 4 * hi;
      float lq = lD[r] + R[rbase + 2048 + qloc] - cb;
      float inv = 1.0f / lq;
      int qgrow = qt * 64 + qg * 32 + qloc;
      size_t ob = ((size_t)(b * TT + qgrow) << 9) + hd * 64;
      att[ob + l31] = (f16)(o0[r] * inv);
      att[ob + 32 + l31] = (f16)(o1[r] * inv);
    }
  }
}

// ---------------- output projection: out = att @ Wo^T + bo (f32) ----------
__global__ __launch_bounds__(256) void gemm_out(const f16* __restrict__ A,
                                                const f16* __restrict__ W,
                                                const float* __restrict__ bias,
                                                float* __restrict__ out) {
  __shared__ __align__(16) f16 Alds[64 * 64];
  __shared__ __align__(16) f16 Blds[128 * 64];

  const int nt = blockIdx.x & 3;
  const int mt = blockIdx.x >> 2;
  const int tid = threadIdx.x;
  const int w = tid >> 6, lane = tid & 63;
  const int l15 = lane & 15, lg = lane >> 4;
  const int wm = w >> 1, wn = w & 1;

  f32x4 acc[2][4];
#pragma unroll
  for (int mi = 0; mi < 2; ++mi)
#pragma unroll
    for (int nj = 0; nj < 4; ++nj) acc[mi][nj] = {};

  for (int kt = 0; kt < 8; ++kt) {
#pragma unroll
    for (int i = 0; i < 2; ++i) {
      int g = (i * 4 + w) * 64 + lane;
      int row = g >> 3, jj = g & 7;
      int kb = kt * 128 + ((jj ^ (row & 7)) << 4);
      gload_lds16((const char*)A + (size_t)(mt * 64 + row) * 1024 + kb,
                  (char*)Alds + g * 16);
    }
#pragma unroll
    for (int i = 0; i < 4; ++i) {
      int g = (i * 4 + w) * 64 + lane;
      int row = g >> 3, jj = g & 7;
      int kb = kt * 128 + ((jj ^ (row & 7)) << 4);
      gload_lds16((const char*)W + (size_t)(nt * 128 + row) * 1024 + kb,
                  (char*)Blds + g * 16);
    }
    __syncthreads();

#pragma unroll
    for (int h2 = 0; h2 < 2; ++h2) {
      f16x8 af[2], bf[4];
#pragma unroll
      for (int mi = 0; mi < 2; ++mi) {
        int row = wm * 32 + mi * 16 + l15;
        int bo = (h2 * 64 + (lg << 4)) ^ ((row & 7) << 4);
        af[mi] = *(const f16x8*)((const char*)Alds + row * 128 + bo);
      }
#pragma unroll
      for (int nj = 0; nj < 4; ++nj) {
        int row = wn * 64 + nj * 16 + l15;
        int bo = (h2 * 64 + (lg << 4)) ^ ((row & 7) << 4);
        bf[nj] = *(const f16x8*)((const char*)Blds + row * 128 + bo);
      }
#pragma unroll
      for (int mi = 0; mi < 2; ++mi)
#pragma unroll
        for (int nj = 0; nj < 4; ++nj)
          acc[mi][nj] = __builtin_amdgcn_mfma_f32_16x16x32_f16(
              af[mi], bf[nj], acc[mi][nj], 0, 0, 0);
    }
    __syncthreads();
  }

  const int base_m = mt * 64 + wm * 32;
  const int base_n = nt * 128 + wn * 64;
#pragma unroll
  for (int mi = 0; mi < 2; ++mi)
#pragma unroll
    for (int nj = 0; nj < 4; ++nj) {
      int n = base_n + nj * 16 + l15;
      float bv = bias[n];
#pragma unroll
      for (int r = 0; r < 4; ++r) {
        int m = base_m + mi * 16 + (lg << 2) + r;
        out[(size_t)m * 512 + n] = acc[mi][nj][r] + bv;
      }
    }
}

// ---------------- host launch ----------------
extern "C" void kernel_launch(void* const* d_in, const int* in_sizes, int n_in,
                              void* d_out, int out_size, void* d_ws, size_t ws_size,
                              hipStream_t stream) {
  (void)in_sizes; (void)n_in; (void)out_size; (void)ws_size;
  const float* q = (const float*)d_in[0];
  const float* k = (const float*)d_in[1];
  const float* v = (const float*)d_in[2];
  const int* mask = (const int*)d_in[3];
  const float* Wq = (const float*)d_in[4];
  const float* bq = (const float*)d_in[5];
  const float* Wk = (const float*)d_in[6];
  const float* bk = (const float*)d_in[7];
  const float* Wv = (const float*)d_in[8];
  const float* bv = (const float*)d_in[9];
  const float* Wo = (const float*)d_in[10];
  const float* bo = (const float*)d_in[11];

  char* ws = (char*)d_ws;
  const size_t SZ = (size_t)8192 * 512 * 2;
  f16* q16 = (f16*)(ws + 0 * SZ);
  f16* k16 = (f16*)(ws + 1 * SZ);
  f16* v16 = (f16*)(ws + 2 * SZ);
  f16* qhp = (f16*)(ws + 3 * SZ);
  f16* khp = (f16*)(ws + 4 * SZ);
  f16* vhT = (f16*)(ws + 5 * SZ);
  f16* w16 = (f16*)(ws + 6 * SZ);
  f16* wq16 = w16;
  f16* wk16 = w16 + 262144;
  f16* wv16 = w16 + 2 * 262144;
  f16* wo16 = w16 + 3 * 262144;
  float* cntb = (float*)(ws + 6 * SZ + 4 * 262144 * sizeof(f16));
  f16* att = (f16*)(ws + 0 * SZ);

  prep<<<13316, 256, 0, stream>>>(q, k, v, Wq, Wk, Wv, Wo, mask, q16, w16, cntb);

  const float scale = 0.044194173824159216f * 1.4426950408889634f;
  gemm_qkv<<<1536, 128, 0, stream>>>(q16, k16, v16, wq16, wk16, wv16, bq, bk, bv,
                                     mask, qhp, khp, vhT, scale);

  attn_k<<<1024, 256, 0, stream>>>(qhp, khp, vhT, cntb, att);

  gemm_out<<<512, 256, 0, stream>>>(att, wo16, bo, (float*)d_out);
}